// Round 10
// baseline (439.841 us; speedup 1.0000x reference)
//
#include <hip/hip_runtime.h>
#include <hip/hip_bf16.h>

// Problem constants (from reference)
#define N_NODES  100000
#define N_EDGES  400000
#define N_GRAPHS 4000
#define IN_DIM   128
#define HID      512
#define N_DESC   200
#define N_CLASSES 2
#define MLP1_OUT 500
#define MLP2_OUT 100
#define XIN_DIM  (HID + N_DESC)   // 712
#define XIN_PAD  768              // K padded to multiple of 64

#define SCAN_CHUNK 1024
#define NCHK ((N_NODES + SCAN_CHUNK - 1) / SCAN_CHUNK)   // 98

typedef __hip_bfloat16  bf16;
typedef __hip_bfloat162 bf16x2;
typedef short s8v  __attribute__((ext_vector_type(8)));   // 8 bf16 (4 VGPRs)
typedef float f32x4 __attribute__((ext_vector_type(4)));

// ---------------------------------------------------------------------------
// Dtype-generic helpers (FT = float or bf16), all produce fp32.
// ---------------------------------------------------------------------------
__device__ __forceinline__ float ldf(const float* p, size_t i) { return p[i]; }
__device__ __forceinline__ float ldf(const bf16* p, size_t i)  { return __bfloat162float(p[i]); }

__device__ __forceinline__ short f2bs(float x) {
    bf16 h = __float2bfloat16(x);
    return __builtin_bit_cast(short, h);
}

// async global->LDS, 16B per lane; LDS dest = wave-uniform base + lane*16
__device__ __forceinline__ void gld16(const short* g, short* l) {
    __builtin_amdgcn_global_load_lds(
        (const __attribute__((address_space(1))) unsigned int*)g,
        (__attribute__((address_space(3))) unsigned int*)l, 16, 0, 0);
}

#define MEMFENCE asm volatile("" ::: "memory")

// ---------------------------------------------------------------------------
// Runtime dtype detection (flag: 0=fp32, 1=bf16)
// ---------------------------------------------------------------------------
__global__ __launch_bounds__(256)
void detect_dtype_kernel(const unsigned* __restrict__ words, unsigned nw,
                         int* __restrict__ flag)
{
    __shared__ int s_cnt;
    if (threadIdx.x == 0) s_cnt = 0;
    __syncthreads();
    const int SAMPLES = 2048;
    int sane = 0;
    for (int i = threadIdx.x; i < SAMPLES; i += 256) {
        size_t idx = (size_t)(((unsigned long long)i * 2654435761ull) % nw);
        unsigned w = words[idx];
        float f = __uint_as_float((w & 0xFFFFu) << 16);
        float a = fabsf(f);
        if (f == 0.0f || (a > 1e-8f && a < 1e8f)) sane++;
    }
    atomicAdd(&s_cnt, sane);
    __syncthreads();
    if (threadIdx.x == 0) *flag = (s_cnt * 10 > SAMPLES * 6) ? 1 : 0;
}

// ---------------------------------------------------------------------------
// Fused weight prep (UNIFIED: runtime dtype branch): weights -> transposed
// bf16 [N][K] (zero-pad), biases -> fp32 (zero-pad). Segments: W1t 65536 |
// W2t 262144 | lw1t 393216 | lw2t 65536 | b1f 512 | b2f 512 | lb1f 512 |
// lb2f 128  (total 788096)
// ---------------------------------------------------------------------------
template<typename FT>
__device__ __forceinline__
void prep_body(int i, const FT* W1, const FT* W2, const FT* lw1, const FT* lw2,
               const FT* b1, const FT* b2, const FT* lb1, const FT* lb2,
               short* W1t, short* W2t, short* lw1t, short* lw2t,
               float* b1f, float* b2f, float* lb1f, float* lb2f)
{
    if (i < 65536) {            // W1t [512][128] <- W1 [128,512]
        int n = i >> 7, k = i & 127;
        W1t[i] = f2bs(ldf(W1, (size_t)k * HID + n));
        return;
    }
    i -= 65536;
    if (i < 262144) {           // W2t [512][512] <- W2 [512,512]
        int n = i >> 9, k = i & 511;
        W2t[i] = f2bs(ldf(W2, (size_t)k * HID + n));
        return;
    }
    i -= 262144;
    if (i < 393216) {           // lw1t [512][768] <- lw1 [712,500], zero-pad
        int n = i / XIN_PAD, k = i - n * XIN_PAD;
        lw1t[i] = (n < MLP1_OUT && k < XIN_DIM)
                      ? f2bs(ldf(lw1, (size_t)k * MLP1_OUT + n)) : (short)0;
        return;
    }
    i -= 393216;
    if (i < 65536) {            // lw2t [128][512] <- lw2 [500,100], zero-pad
        int n = i >> 9, k = i & 511;
        lw2t[i] = (n < MLP2_OUT && k < MLP1_OUT)
                      ? f2bs(ldf(lw2, (size_t)k * MLP2_OUT + n)) : (short)0;
        return;
    }
    i -= 65536;
    if (i < 512) { b1f[i] = ldf(b1, i); return; }
    i -= 512;
    if (i < 512) { b2f[i] = ldf(b2, i); return; }
    i -= 512;
    if (i < 512) { lb1f[i] = (i < MLP1_OUT) ? ldf(lb1, i) : 0.f; return; }
    i -= 512;
    if (i < 128) { lb2f[i] = (i < MLP2_OUT) ? ldf(lb2, i) : 0.f; return; }
}

__global__ __launch_bounds__(256)
void prep_weights_kernel(const void* __restrict__ W1, const void* __restrict__ W2,
                         const void* __restrict__ lw1, const void* __restrict__ lw2,
                         const void* __restrict__ b1, const void* __restrict__ b2,
                         const void* __restrict__ lb1, const void* __restrict__ lb2,
                         short* __restrict__ W1t, short* __restrict__ W2t,
                         short* __restrict__ lw1t, short* __restrict__ lw2t,
                         float* __restrict__ b1f, float* __restrict__ b2f,
                         float* __restrict__ lb1f, float* __restrict__ lb2f,
                         const int* __restrict__ flag)
{
    int i = blockIdx.x * 256 + threadIdx.x;
    if (*flag == 0)
        prep_body<float>(i, (const float*)W1, (const float*)W2, (const float*)lw1,
                         (const float*)lw2, (const float*)b1, (const float*)b2,
                         (const float*)lb1, (const float*)lb2,
                         W1t, W2t, lw1t, lw2t, b1f, b2f, lb1f, lb2f);
    else
        prep_body<bf16>(i, (const bf16*)W1, (const bf16*)W2, (const bf16*)lw1,
                        (const bf16*)lw2, (const bf16*)b1, (const bf16*)b2,
                        (const bf16*)lb1, (const bf16*)lb2,
                        W1t, W2t, lw1t, lw2t, b1f, b2f, lb1f, lb2f);
}

// ---------------------------------------------------------------------------
// CSR build: deg histogram -> two-level exclusive scan -> fill
// ---------------------------------------------------------------------------
__global__ __launch_bounds__(256)
void deg_kernel(const int* __restrict__ dst, int* __restrict__ deg)
{
    int e = blockIdx.x * 256 + threadIdx.x;
    if (e < N_EDGES) atomicAdd(&deg[dst[e]], 1);
}

__global__ __launch_bounds__(256)
void scan_partial_kernel(const int* __restrict__ deg, int* __restrict__ part)
{
    int c = blockIdx.x, t = threadIdx.x;
    int i0 = c * SCAN_CHUNK + t * 4;
    int s = 0;
#pragma unroll
    for (int j = 0; j < 4; j++) {
        int i = i0 + j;
        if (i < N_NODES) s += deg[i];
    }
    __shared__ int red[256];
    red[t] = s;
    __syncthreads();
    for (int off = 128; off > 0; off >>= 1) {
        if (t < off) red[t] += red[t + off];
        __syncthreads();
    }
    if (t == 0) part[c] = red[0];
}

__global__ void scan_parts_kernel(int* __restrict__ part, int* __restrict__ edge_start)
{
    int run = 0;
    for (int c = 0; c < NCHK; c++) { int v = part[c]; part[c] = run; run += v; }
    edge_start[N_NODES] = run;
}

// also initializes cursor[] (saves a dispatch)
__global__ __launch_bounds__(256)
void scan_final_kernel(const int* __restrict__ deg, const int* __restrict__ part,
                       int* __restrict__ edge_start, int* __restrict__ cursor)
{
    int c = blockIdx.x, t = threadIdx.x;
    int i0 = c * SCAN_CHUNK + t * 4;
    int d[4];
    int tsum = 0;
#pragma unroll
    for (int j = 0; j < 4; j++) {
        int i = i0 + j;
        d[j] = (i < N_NODES) ? deg[i] : 0;
        tsum += d[j];
    }
    __shared__ int s[256];
    s[t] = tsum;
    __syncthreads();
    for (int off = 1; off < 256; off <<= 1) {
        int v = (t >= off) ? s[t - off] : 0;
        __syncthreads();
        s[t] += v;
        __syncthreads();
    }
    int run = part[c] + s[t] - tsum;
#pragma unroll
    for (int j = 0; j < 4; j++) {
        int i = i0 + j;
        if (i < N_NODES) { edge_start[i] = run; cursor[i] = run; run += d[j]; }
    }
}

__global__ __launch_bounds__(256)
void fill_kernel(const int* __restrict__ src, const int* __restrict__ dst,
                 int* __restrict__ cursor, int* __restrict__ csr_src)
{
    int e = blockIdx.x * 256 + threadIdx.x;
    if (e >= N_EDGES) return;
    int p = atomicAdd(&cursor[dst[e]], 1);
    csr_src[p] = src[e];
}

// gstart[g] = first node index with node2graph >= g (node2graph sorted)
__global__ __launch_bounds__(256)
void gstart_kernel(const int* __restrict__ n2g, int* __restrict__ gstart)
{
    int n = blockIdx.x * 256 + threadIdx.x;
    if (n > N_NODES) return;
    if (n == N_NODES) {
        int last = n2g[N_NODES - 1];
        for (int g = last + 1; g <= N_GRAPHS; g++) gstart[g] = N_NODES;
        return;
    }
    int v = n2g[n];
    int prev = (n == 0) ? -1 : n2g[n - 1];
    for (int g = prev + 1; g <= v; g++) gstart[g] = n;
}

// ---------------------------------------------------------------------------
// Layer-1 gather (UNIFIED): agg1[n,0:128] = sum_{e: dst=n} feat[src[e],0:128]
// ---------------------------------------------------------------------------
__global__ __launch_bounds__(256)
void gather_feat_kernel(const void* __restrict__ feat_, const int* __restrict__ edge_start,
                        const int* __restrict__ csr_src, bf16* __restrict__ agg1,
                        const int* __restrict__ flag)
{
    int n = blockIdx.x * 4 + (threadIdx.x >> 6);
    if (n >= N_NODES) return;
    int lane = threadIdx.x & 63;
    int e0 = edge_start[n], e1 = edge_start[n + 1];
    float2 acc = {0.f, 0.f};
    if (*flag == 0) {
        const float* feat = (const float*)feat_;
        for (int i = e0; i < e1; i++) {
            int s = csr_src[i];
            float2 f = ((const float2*)(feat + (size_t)s * IN_DIM))[lane];
            acc.x += f.x; acc.y += f.y;
        }
    } else {
        const bf16* feat = (const bf16*)feat_;
        for (int i = e0; i < e1; i++) {
            int s = csr_src[i];
            float2 f = __bfloat1622float2(((const bf16x2*)(feat + (size_t)s * IN_DIM))[lane]);
            acc.x += f.x; acc.y += f.y;
        }
    }
    bf16x2 p;
    p.x = __float2bfloat16(acc.x);
    p.y = __float2bfloat16(acc.y);
    ((bf16x2*)(agg1 + (size_t)n * IN_DIM))[lane] = p;
}

// ---------------------------------------------------------------------------
// MFMA bf16 GEMM — round-7 schedule (BK=32 double buffer, counted vmcnt,
// register diet, __launch_bounds__(256,4)). ACT template flag:
//   ACT=1: C = relu(A @ Bt^T + bias)   (layer-1 / head GEMMs)
//   ACT=0: C = A @ Bt^T                (layer-2 G = h1 @ W2, pre-bias/relu)
// ---------------------------------------------------------------------------
template<int NCT, int ACT>
__global__ __launch_bounds__(256, 4)
void mfma_gemm_kernel(const short* __restrict__ A, const short* __restrict__ Bt,
                      const float* __restrict__ biasf, bf16* __restrict__ Cout,
                      int M, int K, int nrt)
{
    // K-loop: 2 bufs x (As 4096 + Bs 4096) = 16384 shorts.
    // Epilogue Cs alias needs 128*136 = 17408 shorts -> smem = 17408.
    __shared__ short smem[17408];
    short* Cs = smem;

    // XCD-colocating decode
    const int b  = blockIdx.x;
    const int r8 = b & 7;
    const int t0 = b >> 3;
    const int x  = (t0 / NCT) * 8 + r8;
    const int y  = t0 % NCT;
    if (x >= nrt) return;
    const int row0 = x * 128;
    const int col0 = y * 128;

    const int tid  = threadIdx.x;
    const int lane = tid & 63;
    const int w    = tid >> 6;
    const int wr = w >> 1, wc = w & 1;
    const int m  = lane & 15, q = lane >> 4;

    // Staging (BK=32): per wave 2 A-chunks + 2 B-chunks (1 KB each).
    const int rr = lane >> 2;
    const int dc = ((lane & 3) ^ ((lane >> 3) & 3)) * 8;
    const short* pA = A  + (size_t)(row0 + w * 32 + rr) * K + dc;  // OOB rows: in-ws garbage
    const short* pB = Bt + (size_t)(col0 + w * 32 + rr) * K + dc;  // Bt padded to grid cols
    const int cOff = 16 * K;            // chunk-1 row offset (wave-uniform)

    // Fragment-read swizzled slot offset (shorts): row m, granule q
    const int so = (q ^ ((m >> 1) & 3)) * 8;

    f32x4 acc[4][4];
#pragma unroll
    for (int i = 0; i < 4; i++)
#pragma unroll
        for (int j = 0; j < 4; j++) acc[i][j] = {0.f, 0.f, 0.f, 0.f};

    // Prologue: stage tile 0 into buf0 (4 loads/wave outstanding)
    {
        short* d = smem + w * 1024;
        gld16(pA, d);               gld16(pA + cOff, d + 512);
        gld16(pB, d + 4096);        gld16(pB + cOff, d + 4096 + 512);
        pA += 32; pB += 32;
    }

    const int NT = K >> 5;
    for (int t = 0; t < NT; ++t) {
        const int boff = (t & 1) << 13;         // buf select (*8192 shorts)
        if (t + 1 < NT) {
            short* d = smem + (8192 - boff) + w * 1024;   // next buf
            gld16(pA, d);           gld16(pA + cOff, d + 512);
            gld16(pB, d + 4096);    gld16(pB + cOff, d + 4096 + 512);
            pA += 32; pB += 32;
            // tile t's 4 loads retired; tile t+1's 4 stay in flight (T4)
            asm volatile("s_waitcnt vmcnt(4)" ::: "memory");
        } else {
            asm volatile("s_waitcnt vmcnt(0)" ::: "memory");
        }
        __builtin_amdgcn_s_barrier();   // raw: no implicit vmcnt(0) drain
        MEMFENCE;

        const short* Ab = smem + boff;
        const short* Bb = smem + boff + 4096;
        s8v av[4], bv[4];
#pragma unroll
        for (int rt = 0; rt < 4; rt++)
            av[rt] = *(const s8v*)&Ab[(wr * 64 + rt * 16 + m) * 32 + so];
#pragma unroll
        for (int ct = 0; ct < 4; ct++)
            bv[ct] = *(const s8v*)&Bb[(wc * 64 + ct * 16 + m) * 32 + so];
#pragma unroll
        for (int rt = 0; rt < 4; rt++)
#pragma unroll
            for (int ct = 0; ct < 4; ct++)
                acc[rt][ct] = __builtin_amdgcn_mfma_f32_16x16x32_bf16(
                    av[rt], bv[ct], acc[rt][ct], 0, 0, 0);

        MEMFENCE;
        __builtin_amdgcn_s_barrier();   // buf[t&1] free for reuse at t+1's stage
        MEMFENCE;
    }

    // Epilogue phase 1: (ACT: bias + relu) -> bf16 C-tile into LDS (pad-136)
#pragma unroll
    for (int rt = 0; rt < 4; rt++) {
#pragma unroll
        for (int ct = 0; ct < 4; ct++) {
            int lcol = wc * 64 + ct * 16 + m;
            float bv = ACT ? biasf[col0 + lcol] : 0.f;
#pragma unroll
            for (int reg = 0; reg < 4; reg++) {
                int lrow = wr * 64 + rt * 16 + q * 4 + reg;
                float v = acc[rt][ct][reg];
                if constexpr (ACT) {
                    v += bv;
                    v = v > 0.f ? v : 0.f;
                }
                Cs[lrow * 136 + lcol] = f2bs(v);
            }
        }
    }
    __syncthreads();

    // Epilogue phase 2: coalesced 16B stores (wave = 4 full 256B row segments)
#pragma unroll
    for (int it = 0; it < 8; it++) {
        int idx = it * 256 + tid;
        int r = idx >> 4;
        int c = (idx & 15) * 8;
        int row = row0 + r;
        if (row < M)
            *(float4*)&Cout[(size_t)row * HID + col0 + c] =
                *(const float4*)&Cs[r * 136 + c];
    }
}

// ---------------------------------------------------------------------------
// FUSED layer-2 gather + bias + relu + graph mean-pool numerator, NO atomics.
// Round-10: block (4 waves) per graph, wave w strides nodes by 4, and now
// processes TWO nodes concurrently (n, n+4; advance by 8) with independent
// accumulator sets -> 2 dependent-load chains in flight per wave (round-9
// PMC: occupancy 62% but 2.78 TB/s vs gather_h's 4.17 -> per-wave ILP was
// the residual limiter, not TLP). Wave-uniform guards (edge counts uniform
// across lanes) -> no divergence.
//   hg[g,:] = sum_n relu( sum_{e: dst=n} G[csr_src[e],:] + b2 ),  G = h1@W2
// ---------------------------------------------------------------------------
__global__ __launch_bounds__(256)
void gather_pool_kernel(const bf16* __restrict__ G, const int* __restrict__ edge_start,
                        const int* __restrict__ csr_src, const int* __restrict__ gstart,
                        const float* __restrict__ b2f, float* __restrict__ hg)
{
    __shared__ float red[4][HID];
    const int g = blockIdx.x;
    const int tid = threadIdx.x;
    const int lane = tid & 63;
    const int w = tid >> 6;

    float bj[8];
    {
        const float4* bp = (const float4*)(b2f + lane * 8);
        float4 b0 = bp[0], b1 = bp[1];
        bj[0] = b0.x; bj[1] = b0.y; bj[2] = b0.z; bj[3] = b0.w;
        bj[4] = b1.x; bj[5] = b1.y; bj[6] = b1.z; bj[7] = b1.w;
    }

    const int s0 = gstart[g], s1 = gstart[g + 1];
    float hacc[8];
#pragma unroll
    for (int j = 0; j < 8; j++) hacc[j] = 0.f;

    for (int n = s0 + w; n < s1; n += 8) {
        const int nB = n + 4;
        const bool hasB = (nB < s1);
        const int a0 = edge_start[n],  a1 = edge_start[n + 1];
        const int b0 = hasB ? edge_start[nB] : 0;
        const int b1e = hasB ? edge_start[nB + 1] : 0;
        const int la = a1 - a0;
        const int lb = b1e - b0;
        const int L = la > lb ? la : lb;

        float raccA[8], raccB[8];
#pragma unroll
        for (int j = 0; j < 8; j++) { raccA[j] = 0.f; raccB[j] = 0.f; }

        for (int i = 0; i < L; ++i) {
            // issue both rows' loads back-to-back (independent chains)
            if (i < la) {
                int s = csr_src[a0 + i];
                float4 r = ((const float4*)(G + (size_t)s * HID))[lane];
                const bf16x2* p = (const bf16x2*)&r;
#pragma unroll
                for (int qq = 0; qq < 4; qq++) {
                    float2 f = __bfloat1622float2(p[qq]);
                    raccA[2 * qq] += f.x; raccA[2 * qq + 1] += f.y;
                }
            }
            if (i < lb) {
                int s = csr_src[b0 + i];
                float4 r = ((const float4*)(G + (size_t)s * HID))[lane];
                const bf16x2* p = (const bf16x2*)&r;
#pragma unroll
                for (int qq = 0; qq < 4; qq++) {
                    float2 f = __bfloat1622float2(p[qq]);
                    raccB[2 * qq] += f.x; raccB[2 * qq + 1] += f.y;
                }
            }
        }
#pragma unroll
        for (int j = 0; j < 8; j++) {
            float vA = raccA[j] + bj[j];
            hacc[j] += (vA > 0.f ? vA : 0.f);
        }
        if (hasB) {
#pragma unroll
            for (int j = 0; j < 8; j++) {
                float vB = raccB[j] + bj[j];
                hacc[j] += (vB > 0.f ? vB : 0.f);
            }
        }
    }

    // LDS reduce 4 partial rows (epilogue cost negligible vs gather traffic)
    ((float4*)&red[w][lane * 8])[0] = make_float4(hacc[0], hacc[1], hacc[2], hacc[3]);
    ((float4*)&red[w][lane * 8])[1] = make_float4(hacc[4], hacc[5], hacc[6], hacc[7]);
    __syncthreads();
#pragma unroll
    for (int c = tid; c < HID; c += 256) {
        hg[(size_t)g * HID + c] = red[0][c] + red[1][c] + red[2][c] + red[3][c];
    }
}

// xinb[g, c] (bf16, stride 768) = c<512: hg/cnt | c<712: desc | else 0  (UNIFIED)
__global__ __launch_bounds__(256)
void build_xin_kernel(const float* __restrict__ hg, const int* __restrict__ gstart,
                      const void* __restrict__ desc_, bf16* __restrict__ xinb,
                      const int* __restrict__ flag)
{
    int idx = blockIdx.x * 256 + threadIdx.x;
    if (idx >= N_GRAPHS * XIN_PAD) return;
    int g = idx / XIN_PAD;
    int c = idx - g * XIN_PAD;
    float v;
    if (c < HID) {
        float cnt = (float)(gstart[g + 1] - gstart[g]);
        v = hg[(size_t)g * HID + c] / (cnt > 1.0f ? cnt : 1.0f);
    } else if (c < XIN_DIM) {
        size_t di = (size_t)g * N_DESC + (c - HID);
        v = (*flag == 0) ? ((const float*)desc_)[di]
                         : __bfloat162float(((const bf16*)desc_)[di]);
    } else {
        v = 0.f;
    }
    xinb[idx] = __float2bfloat16(v);
}

// out[g, c] = x2b[g,:100] @ cw[:,c] + cb[c]  (UNIFIED; out dtype by flag)
__global__ __launch_bounds__(256)
void final_layer_kernel(const bf16* __restrict__ x2b, const void* __restrict__ cw_,
                        const void* __restrict__ cb_, void* __restrict__ out_,
                        const int* __restrict__ flag)
{
    int i = blockIdx.x * 256 + threadIdx.x;
    if (i >= N_GRAPHS * N_CLASSES) return;
    int r = i >> 1, c = i & 1;
    const bf16* x = x2b + (size_t)r * HID;   // stride 512, cols 0..99 valid
    if (*flag == 0) {
        const float* cw = (const float*)cw_;
        float acc = ((const float*)cb_)[c];
#pragma unroll 4
        for (int k = 0; k < MLP2_OUT; k++)
            acc += __bfloat162float(x[k]) * cw[k * N_CLASSES + c];
        ((float*)out_)[i] = acc;
    } else {
        const bf16* cw = (const bf16*)cw_;
        float acc = __bfloat162float(((const bf16*)cb_)[c]);
#pragma unroll 4
        for (int k = 0; k < MLP2_OUT; k++)
            acc += __bfloat162float(x[k]) * __bfloat162float(cw[k * N_CLASSES + c]);
        ((bf16*)out_)[i] = __float2bfloat16(acc);
    }
}

// ---------------------------------------------------------------------------
static inline size_t align_up(size_t x, size_t a) { return (x + a - 1) & ~(a - 1); }
static inline int swgrid(int nrt, int nct) { return ((nrt + 7) / 8) * 8 * nct; }

extern "C" void kernel_launch(void* const* d_in, const int* in_sizes, int n_in,
                              void* d_out, int out_size, void* d_ws, size_t ws_size,
                              hipStream_t stream)
{
    const void* features    = d_in[0];
    const void* descriptors = d_in[1];
    const int*  src         = (const int*)d_in[2];
    const int*  dst         = (const int*)d_in[3];
    const int*  node2graph  = (const int*)d_in[4];
    const void* W1          = d_in[5];
    const void* b1          = d_in[6];
    const void* W2          = d_in[7];
    const void* b2          = d_in[8];
    const void* lw1         = d_in[9];
    const void* lb1         = d_in[10];
    const void* lw2         = d_in[11];
    const void* lb2         = d_in[12];
    const void* cw          = d_in[13];
    const void* cb          = d_in[14];
    (void)in_sizes; (void)n_in; (void)out_size; (void)ws_size;

    // ---- Workspace layout (fixed ~218 MB; proven ws >= ~239 MB) ----
    // R_A (102.4 MB): agg1 bf16 [100000,128] -> G bf16 [100000,512] (=h1@W2)
    //                 -> head buffers (xinb @0, x1b @8MB, x2b @16MB)
    // R_B (102.4 MB): h1 bf16 [100000,512]
    char* ws = (char*)d_ws;
    size_t off = 0;
    bf16* agg1 = (bf16*)(ws + off);
    bf16* G    = (bf16*)(ws + off);   // layer-2 pre-bias product h1@W2
    bf16* xinb = (bf16*)(ws + off);
    bf16* x1b  = (bf16*)(ws + off + (size_t)8 * 1024 * 1024);
    bf16* x2b  = (bf16*)(ws + off + (size_t)16 * 1024 * 1024);
    off = align_up(off + (size_t)N_NODES * HID * sizeof(bf16), 256);   // 102.4 MB
    bf16* h1 = (bf16*)(ws + off);
    off = align_up(off + (size_t)N_NODES * HID * sizeof(bf16), 256);   // +102.4 MB
    float* hg = (float*)(ws + off);
    off = align_up(off + (size_t)N_GRAPHS * HID * sizeof(float), 256); // +8.19 MB
    int* dflag = (int*)(ws + off);          off = align_up(off + 256, 256);
    int* edge_start = (int*)(ws + off);     off = align_up(off + (N_NODES + 1) * 4, 256);
    int* cursor = (int*)(ws + off);         off = align_up(off + N_NODES * 4, 256);
    int* csr_src = (int*)(ws + off);        off = align_up(off + N_EDGES * 4, 256);
    int* part = (int*)(ws + off);           off = align_up(off + NCHK * 4, 256);
    int* deg = (int*)(ws + off);            off = align_up(off + N_NODES * 4, 256);
    int* gstart = (int*)(ws + off);         off = align_up(off + (N_GRAPHS + 1) * 4, 256);
    short* W1t  = (short*)(ws + off);       off = align_up(off + (size_t)HID * IN_DIM * 2, 256);
    short* W2t  = (short*)(ws + off);       off = align_up(off + (size_t)HID * HID * 2, 256);
    short* lw1t = (short*)(ws + off);       off = align_up(off + (size_t)512 * XIN_PAD * 2, 256);
    short* lw2t = (short*)(ws + off);       off = align_up(off + (size_t)128 * HID * 2, 256);
    float* b1f  = (float*)(ws + off);       off = align_up(off + 512 * 4, 256);
    float* b2f  = (float*)(ws + off);       off = align_up(off + 512 * 4, 256);
    float* lb1f = (float*)(ws + off);       off = align_up(off + 512 * 4, 256);
    float* lb2f = (float*)(ws + off);       off = align_up(off + 128 * 4, 256);

    // ---- Detect float-tensor dtype (flag: 0=fp32, 1=bf16) ----
    detect_dtype_kernel<<<1, 256, 0, stream>>>(
        (const unsigned*)features, (unsigned)(N_NODES * IN_DIM / 2), dflag);

    // ---- Weight prep (single unified launch) ----
    {
        int nblk = (788096 + 255) / 256;
        prep_weights_kernel<<<nblk, 256, 0, stream>>>(
            W1, W2, lw1, lw2, b1, b2, lb1, lb2,
            W1t, W2t, lw1t, lw2t, b1f, b2f, lb1f, lb2f, dflag);
    }

    // ---- CSR build (counting sort by dst) + graph ranges ----
    hipMemsetAsync(deg, 0, N_NODES * 4, stream);
    deg_kernel<<<(N_EDGES + 255) / 256, 256, 0, stream>>>(dst, deg);
    scan_partial_kernel<<<NCHK, 256, 0, stream>>>(deg, part);
    scan_parts_kernel<<<1, 1, 0, stream>>>(part, edge_start);
    scan_final_kernel<<<NCHK, 256, 0, stream>>>(deg, part, edge_start, cursor);
    fill_kernel<<<(N_EDGES + 255) / 256, 256, 0, stream>>>(src, dst, cursor, csr_src);
    gstart_kernel<<<(N_NODES + 256) / 256, 256, 0, stream>>>(node2graph, gstart);

    // ---- Layer 1: gather -> agg1 (bf16), MFMA GEMM (bias+relu) -> h1 ----
    gather_feat_kernel<<<N_NODES / 4, 256, 0, stream>>>(
        features, edge_start, csr_src, agg1, dflag);
    {
        int nrt = (N_NODES + 127) / 128;   // 782
        mfma_gemm_kernel<4, 1><<<swgrid(nrt, 4), 256, 0, stream>>>(
            (const short*)agg1, W1t, b1f, h1, N_NODES, IN_DIM, nrt);
    }

    // ---- Layer 2 (reassociated, matches reference order):
    //      G = h1 @ W2 (no bias/relu), then fused gather+bias+relu+pool ----
    {
        int nrt = (N_NODES + 127) / 128;
        mfma_gemm_kernel<4, 0><<<swgrid(nrt, 4), 256, 0, stream>>>(
            (const short*)h1, W2t, b2f /*unused*/, G, N_NODES, HID, nrt);
    }
    gather_pool_kernel<<<N_GRAPHS, 256, 0, stream>>>(
        G, edge_start, csr_src, gstart, b2f, hg);

    // ---- Head (all MFMA; padded-K chaining) ----
    {
        int nthr = (N_GRAPHS * XIN_PAD + 255) / 256;
        build_xin_kernel<<<nthr, 256, 0, stream>>>(
            hg, gstart, descriptors, xinb, dflag);
    }
    {   // x1b[4000,512] = relu(xinb[4000,768] @ lw1t^T + lb1f)
        int nrt = (N_GRAPHS + 127) / 128;  // 32
        mfma_gemm_kernel<4, 1><<<swgrid(nrt, 4), 256, 0, stream>>>(
            (const short*)xinb, lw1t, lb1f, x1b, N_GRAPHS, XIN_PAD, nrt);
    }
    {   // x2b cols 0..127 (stride 512) = relu(x1b @ lw2t^T + lb2f)
        int nrt = (N_GRAPHS + 127) / 128;
        mfma_gemm_kernel<1, 1><<<swgrid(nrt, 1), 256, 0, stream>>>(
            (const short*)x1b, lw2t, lb2f, x2b, N_GRAPHS, HID, nrt);
    }
    {
        int nthr = (N_GRAPHS * N_CLASSES + 255) / 256;
        final_layer_kernel<<<nthr, 256, 0, stream>>>(
            x2b, cw, cb, d_out, dflag);
    }
}

// Round 11
// 435.226 us; speedup vs baseline: 1.0106x; 1.0106x over previous
//
#include <hip/hip_runtime.h>
#include <hip/hip_bf16.h>

// Problem constants (from reference)
#define N_NODES  100000
#define N_EDGES  400000
#define N_GRAPHS 4000
#define IN_DIM   128
#define HID      512
#define N_DESC   200
#define N_CLASSES 2
#define MLP1_OUT 500
#define MLP2_OUT 100
#define XIN_DIM  (HID + N_DESC)   // 712
#define XIN_PAD  768              // K padded to multiple of 64

#define SCAN_CHUNK 1024
#define NCHK ((N_NODES + SCAN_CHUNK - 1) / SCAN_CHUNK)   // 98

typedef __hip_bfloat16  bf16;
typedef __hip_bfloat162 bf16x2;
typedef short s8v  __attribute__((ext_vector_type(8)));   // 8 bf16 (4 VGPRs)
typedef float f32x4 __attribute__((ext_vector_type(4)));

// ---------------------------------------------------------------------------
// Dtype-generic helpers (FT = float or bf16), all produce fp32.
// ---------------------------------------------------------------------------
__device__ __forceinline__ float ldf(const float* p, size_t i) { return p[i]; }
__device__ __forceinline__ float ldf(const bf16* p, size_t i)  { return __bfloat162float(p[i]); }

__device__ __forceinline__ short f2bs(float x) {
    bf16 h = __float2bfloat16(x);
    return __builtin_bit_cast(short, h);
}

// async global->LDS, 16B per lane; LDS dest = wave-uniform base + lane*16
__device__ __forceinline__ void gld16(const short* g, short* l) {
    __builtin_amdgcn_global_load_lds(
        (const __attribute__((address_space(1))) unsigned int*)g,
        (__attribute__((address_space(3))) unsigned int*)l, 16, 0, 0);
}

#define MEMFENCE asm volatile("" ::: "memory")

// ---------------------------------------------------------------------------
// Runtime dtype detection (flag: 0=fp32, 1=bf16)
// ---------------------------------------------------------------------------
__global__ __launch_bounds__(256)
void detect_dtype_kernel(const unsigned* __restrict__ words, unsigned nw,
                         int* __restrict__ flag)
{
    __shared__ int s_cnt;
    if (threadIdx.x == 0) s_cnt = 0;
    __syncthreads();
    const int SAMPLES = 2048;
    int sane = 0;
    for (int i = threadIdx.x; i < SAMPLES; i += 256) {
        size_t idx = (size_t)(((unsigned long long)i * 2654435761ull) % nw);
        unsigned w = words[idx];
        float f = __uint_as_float((w & 0xFFFFu) << 16);
        float a = fabsf(f);
        if (f == 0.0f || (a > 1e-8f && a < 1e8f)) sane++;
    }
    atomicAdd(&s_cnt, sane);
    __syncthreads();
    if (threadIdx.x == 0) *flag = (s_cnt * 10 > SAMPLES * 6) ? 1 : 0;
}

// ---------------------------------------------------------------------------
// Fused weight prep (UNIFIED: runtime dtype branch): weights -> transposed
// bf16 [N][K] (zero-pad), biases -> fp32 (zero-pad). Segments: W1t 65536 |
// W2t 262144 | lw1t 393216 | lw2t 65536 | b1f 512 | b2f 512 | lb1f 512 |
// lb2f 128  (total 788096)
// ---------------------------------------------------------------------------
template<typename FT>
__device__ __forceinline__
void prep_body(int i, const FT* W1, const FT* W2, const FT* lw1, const FT* lw2,
               const FT* b1, const FT* b2, const FT* lb1, const FT* lb2,
               short* W1t, short* W2t, short* lw1t, short* lw2t,
               float* b1f, float* b2f, float* lb1f, float* lb2f)
{
    if (i < 65536) {            // W1t [512][128] <- W1 [128,512]
        int n = i >> 7, k = i & 127;
        W1t[i] = f2bs(ldf(W1, (size_t)k * HID + n));
        return;
    }
    i -= 65536;
    if (i < 262144) {           // W2t [512][512] <- W2 [512,512]
        int n = i >> 9, k = i & 511;
        W2t[i] = f2bs(ldf(W2, (size_t)k * HID + n));
        return;
    }
    i -= 262144;
    if (i < 393216) {           // lw1t [512][768] <- lw1 [712,500], zero-pad
        int n = i / XIN_PAD, k = i - n * XIN_PAD;
        lw1t[i] = (n < MLP1_OUT && k < XIN_DIM)
                      ? f2bs(ldf(lw1, (size_t)k * MLP1_OUT + n)) : (short)0;
        return;
    }
    i -= 393216;
    if (i < 65536) {            // lw2t [128][512] <- lw2 [500,100], zero-pad
        int n = i >> 9, k = i & 511;
        lw2t[i] = (n < MLP2_OUT && k < MLP1_OUT)
                      ? f2bs(ldf(lw2, (size_t)k * MLP2_OUT + n)) : (short)0;
        return;
    }
    i -= 65536;
    if (i < 512) { b1f[i] = ldf(b1, i); return; }
    i -= 512;
    if (i < 512) { b2f[i] = ldf(b2, i); return; }
    i -= 512;
    if (i < 512) { lb1f[i] = (i < MLP1_OUT) ? ldf(lb1, i) : 0.f; return; }
    i -= 512;
    if (i < 128) { lb2f[i] = (i < MLP2_OUT) ? ldf(lb2, i) : 0.f; return; }
}

__global__ __launch_bounds__(256)
void prep_weights_kernel(const void* __restrict__ W1, const void* __restrict__ W2,
                         const void* __restrict__ lw1, const void* __restrict__ lw2,
                         const void* __restrict__ b1, const void* __restrict__ b2,
                         const void* __restrict__ lb1, const void* __restrict__ lb2,
                         short* __restrict__ W1t, short* __restrict__ W2t,
                         short* __restrict__ lw1t, short* __restrict__ lw2t,
                         float* __restrict__ b1f, float* __restrict__ b2f,
                         float* __restrict__ lb1f, float* __restrict__ lb2f,
                         const int* __restrict__ flag)
{
    int i = blockIdx.x * 256 + threadIdx.x;
    if (*flag == 0)
        prep_body<float>(i, (const float*)W1, (const float*)W2, (const float*)lw1,
                         (const float*)lw2, (const float*)b1, (const float*)b2,
                         (const float*)lb1, (const float*)lb2,
                         W1t, W2t, lw1t, lw2t, b1f, b2f, lb1f, lb2f);
    else
        prep_body<bf16>(i, (const bf16*)W1, (const bf16*)W2, (const bf16*)lw1,
                        (const bf16*)lw2, (const bf16*)b1, (const bf16*)b2,
                        (const bf16*)lb1, (const bf16*)lb2,
                        W1t, W2t, lw1t, lw2t, b1f, b2f, lb1f, lb2f);
}

// ---------------------------------------------------------------------------
// CSR build: deg histogram -> two-level exclusive scan -> fill
// ---------------------------------------------------------------------------
__global__ __launch_bounds__(256)
void deg_kernel(const int* __restrict__ dst, int* __restrict__ deg)
{
    int e = blockIdx.x * 256 + threadIdx.x;
    if (e < N_EDGES) atomicAdd(&deg[dst[e]], 1);
}

__global__ __launch_bounds__(256)
void scan_partial_kernel(const int* __restrict__ deg, int* __restrict__ part)
{
    int c = blockIdx.x, t = threadIdx.x;
    int i0 = c * SCAN_CHUNK + t * 4;
    int s = 0;
#pragma unroll
    for (int j = 0; j < 4; j++) {
        int i = i0 + j;
        if (i < N_NODES) s += deg[i];
    }
    __shared__ int red[256];
    red[t] = s;
    __syncthreads();
    for (int off = 128; off > 0; off >>= 1) {
        if (t < off) red[t] += red[t + off];
        __syncthreads();
    }
    if (t == 0) part[c] = red[0];
}

__global__ void scan_parts_kernel(int* __restrict__ part, int* __restrict__ edge_start)
{
    int run = 0;
    for (int c = 0; c < NCHK; c++) { int v = part[c]; part[c] = run; run += v; }
    edge_start[N_NODES] = run;
}

// also initializes cursor[] (saves a dispatch)
__global__ __launch_bounds__(256)
void scan_final_kernel(const int* __restrict__ deg, const int* __restrict__ part,
                       int* __restrict__ edge_start, int* __restrict__ cursor)
{
    int c = blockIdx.x, t = threadIdx.x;
    int i0 = c * SCAN_CHUNK + t * 4;
    int d[4];
    int tsum = 0;
#pragma unroll
    for (int j = 0; j < 4; j++) {
        int i = i0 + j;
        d[j] = (i < N_NODES) ? deg[i] : 0;
        tsum += d[j];
    }
    __shared__ int s[256];
    s[t] = tsum;
    __syncthreads();
    for (int off = 1; off < 256; off <<= 1) {
        int v = (t >= off) ? s[t - off] : 0;
        __syncthreads();
        s[t] += v;
        __syncthreads();
    }
    int run = part[c] + s[t] - tsum;
#pragma unroll
    for (int j = 0; j < 4; j++) {
        int i = i0 + j;
        if (i < N_NODES) { edge_start[i] = run; cursor[i] = run; run += d[j]; }
    }
}

__global__ __launch_bounds__(256)
void fill_kernel(const int* __restrict__ src, const int* __restrict__ dst,
                 int* __restrict__ cursor, int* __restrict__ csr_src)
{
    int e = blockIdx.x * 256 + threadIdx.x;
    if (e >= N_EDGES) return;
    int p = atomicAdd(&cursor[dst[e]], 1);
    csr_src[p] = src[e];
}

// gstart[g] = first node index with node2graph >= g (node2graph sorted)
__global__ __launch_bounds__(256)
void gstart_kernel(const int* __restrict__ n2g, int* __restrict__ gstart)
{
    int n = blockIdx.x * 256 + threadIdx.x;
    if (n > N_NODES) return;
    if (n == N_NODES) {
        int last = n2g[N_NODES - 1];
        for (int g = last + 1; g <= N_GRAPHS; g++) gstart[g] = N_NODES;
        return;
    }
    int v = n2g[n];
    int prev = (n == 0) ? -1 : n2g[n - 1];
    for (int g = prev + 1; g <= v; g++) gstart[g] = n;
}

// ---------------------------------------------------------------------------
// Layer-1 gather (UNIFIED): agg1[n,0:128] = sum_{e: dst=n} feat[src[e],0:128]
// ---------------------------------------------------------------------------
__global__ __launch_bounds__(256)
void gather_feat_kernel(const void* __restrict__ feat_, const int* __restrict__ edge_start,
                        const int* __restrict__ csr_src, bf16* __restrict__ agg1,
                        const int* __restrict__ flag)
{
    int n = blockIdx.x * 4 + (threadIdx.x >> 6);
    if (n >= N_NODES) return;
    int lane = threadIdx.x & 63;
    int e0 = edge_start[n], e1 = edge_start[n + 1];
    float2 acc = {0.f, 0.f};
    if (*flag == 0) {
        const float* feat = (const float*)feat_;
        for (int i = e0; i < e1; i++) {
            int s = csr_src[i];
            float2 f = ((const float2*)(feat + (size_t)s * IN_DIM))[lane];
            acc.x += f.x; acc.y += f.y;
        }
    } else {
        const bf16* feat = (const bf16*)feat_;
        for (int i = e0; i < e1; i++) {
            int s = csr_src[i];
            float2 f = __bfloat1622float2(((const bf16x2*)(feat + (size_t)s * IN_DIM))[lane]);
            acc.x += f.x; acc.y += f.y;
        }
    }
    bf16x2 p;
    p.x = __float2bfloat16(acc.x);
    p.y = __float2bfloat16(acc.y);
    ((bf16x2*)(agg1 + (size_t)n * IN_DIM))[lane] = p;
}

// ---------------------------------------------------------------------------
// MFMA bf16 GEMM — round-7 schedule (BK=32 double buffer, counted vmcnt,
// register diet, __launch_bounds__(256,4)). Template flags:
//   ACT=1: C = relu(A @ Bt^T + bias); ACT=0: C = A @ Bt^T.
//   NRPB: row-tiles per block (processed sequentially, same LDS/regs).
// NRPB=2 for node GEMMs: round-10 two-point fit {K=128, K=512 both ~75us at
// 3.06 block-rounds} gives per-iteration cost ~0, per-block-round fixed cost
// ~24us -> amortize fixed cost over 2 output tiles (grid 3136 -> 1568).
// Heads keep NRPB=1 (grid-starved already).
// ---------------------------------------------------------------------------
template<int NCT, int ACT, int NRPB>
__global__ __launch_bounds__(256, 4)
void mfma_gemm_kernel(const short* __restrict__ A, const short* __restrict__ Bt,
                      const float* __restrict__ biasf, bf16* __restrict__ Cout,
                      int M, int K, int nrt)
{
    // K-loop: 2 bufs x (As 4096 + Bs 4096) = 16384 shorts.
    // Epilogue Cs alias needs 128*136 = 17408 shorts -> smem = 17408.
    __shared__ short smem[17408];
    short* Cs = smem;

    // XCD-colocating decode (xp = row-PAIR index when NRPB=2)
    const int b  = blockIdx.x;
    const int r8 = b & 7;
    const int t0 = b >> 3;
    const int xp = (t0 / NCT) * 8 + r8;
    const int y  = t0 % NCT;
    if (xp * NRPB >= nrt) return;
    const int col0 = y * 128;

    const int tid  = threadIdx.x;
    const int lane = tid & 63;
    const int w    = tid >> 6;
    const int wr = w >> 1, wc = w & 1;
    const int m  = lane & 15, q = lane >> 4;

    // Staging (BK=32): per wave 2 A-chunks + 2 B-chunks (1 KB each).
    const int rr = lane >> 2;
    const int dc = ((lane & 3) ^ ((lane >> 3) & 3)) * 8;
    const int cOff = 16 * K;            // chunk-1 row offset (wave-uniform)

    // Fragment-read swizzled slot offset (shorts): row m, granule q
    const int so = (q ^ ((m >> 1) & 3)) * 8;

    const int NT = K >> 5;

#pragma unroll
    for (int sub = 0; sub < NRPB; ++sub) {
        const int xt = xp * NRPB + sub;
        if (NRPB > 1 && xt >= nrt) break;
        const int row0 = xt * 128;

        if (sub) __syncthreads();   // prev epilogue's Cs reads done before restage

        const short* pA = A  + (size_t)(row0 + w * 32 + rr) * K + dc;  // OOB: in-ws garbage
        const short* pB = Bt + (size_t)(col0 + w * 32 + rr) * K + dc;  // Bt padded

        f32x4 acc[4][4];
#pragma unroll
        for (int i = 0; i < 4; i++)
#pragma unroll
            for (int j = 0; j < 4; j++) acc[i][j] = {0.f, 0.f, 0.f, 0.f};

        // Prologue: stage tile 0 into buf0 (4 loads/wave outstanding)
        {
            short* d = smem + w * 1024;
            gld16(pA, d);               gld16(pA + cOff, d + 512);
            gld16(pB, d + 4096);        gld16(pB + cOff, d + 4096 + 512);
            pA += 32; pB += 32;
        }

        for (int t = 0; t < NT; ++t) {
            const int boff = (t & 1) << 13;         // buf select (*8192 shorts)
            if (t + 1 < NT) {
                short* d = smem + (8192 - boff) + w * 1024;   // next buf
                gld16(pA, d);           gld16(pA + cOff, d + 512);
                gld16(pB, d + 4096);    gld16(pB + cOff, d + 4096 + 512);
                pA += 32; pB += 32;
                // tile t's 4 loads retired; tile t+1's 4 stay in flight (T4)
                asm volatile("s_waitcnt vmcnt(4)" ::: "memory");
            } else {
                asm volatile("s_waitcnt vmcnt(0)" ::: "memory");
            }
            __builtin_amdgcn_s_barrier();   // raw: no implicit vmcnt(0) drain
            MEMFENCE;

            const short* Ab = smem + boff;
            const short* Bb = smem + boff + 4096;
            s8v av[4], bv[4];
#pragma unroll
            for (int rt = 0; rt < 4; rt++)
                av[rt] = *(const s8v*)&Ab[(wr * 64 + rt * 16 + m) * 32 + so];
#pragma unroll
            for (int ct = 0; ct < 4; ct++)
                bv[ct] = *(const s8v*)&Bb[(wc * 64 + ct * 16 + m) * 32 + so];
#pragma unroll
            for (int rt = 0; rt < 4; rt++)
#pragma unroll
                for (int ct = 0; ct < 4; ct++)
                    acc[rt][ct] = __builtin_amdgcn_mfma_f32_16x16x32_bf16(
                        av[rt], bv[ct], acc[rt][ct], 0, 0, 0);

            MEMFENCE;
            __builtin_amdgcn_s_barrier();   // buf[t&1] free for reuse next stage
            MEMFENCE;
        }

        // Epilogue phase 1: (ACT: bias + relu) -> bf16 C-tile in LDS (pad-136)
#pragma unroll
        for (int rt = 0; rt < 4; rt++) {
#pragma unroll
            for (int ct = 0; ct < 4; ct++) {
                int lcol = wc * 64 + ct * 16 + m;
                float bv = ACT ? biasf[col0 + lcol] : 0.f;
#pragma unroll
                for (int reg = 0; reg < 4; reg++) {
                    int lrow = wr * 64 + rt * 16 + q * 4 + reg;
                    float v = acc[rt][ct][reg];
                    if constexpr (ACT) {
                        v += bv;
                        v = v > 0.f ? v : 0.f;
                    }
                    Cs[lrow * 136 + lcol] = f2bs(v);
                }
            }
        }
        __syncthreads();

        // Epilogue phase 2: coalesced 16B stores (wave = 4 full 256B row segs)
#pragma unroll
        for (int it = 0; it < 8; it++) {
            int idx = it * 256 + tid;
            int r = idx >> 4;
            int c = (idx & 15) * 8;
            int row = row0 + r;
            if (row < M)
                *(float4*)&Cout[(size_t)row * HID + col0 + c] =
                    *(const float4*)&Cs[r * 136 + c];
        }
    }
}

// ---------------------------------------------------------------------------
// FUSED layer-2 gather + bias + relu + graph mean-pool numerator, NO atomics.
// Round-9 geometry (reverted round-10 2-node ILP: null, +4 VGPR): block
// (4 waves) per graph, wave w strides nodes by 4, register accumulate, 8KB
// LDS reduction + one coalesced hg write.
//   hg[g,:] = sum_n relu( sum_{e: dst=n} G[csr_src[e],:] + b2 ),  G = h1@W2
// ---------------------------------------------------------------------------
__global__ __launch_bounds__(256)
void gather_pool_kernel(const bf16* __restrict__ G, const int* __restrict__ edge_start,
                        const int* __restrict__ csr_src, const int* __restrict__ gstart,
                        const float* __restrict__ b2f, float* __restrict__ hg)
{
    __shared__ float red[4][HID];
    const int g = blockIdx.x;
    const int tid = threadIdx.x;
    const int lane = tid & 63;
    const int w = tid >> 6;

    float bj[8];
    {
        const float4* bp = (const float4*)(b2f + lane * 8);
        float4 b0 = bp[0], b1 = bp[1];
        bj[0] = b0.x; bj[1] = b0.y; bj[2] = b0.z; bj[3] = b0.w;
        bj[4] = b1.x; bj[5] = b1.y; bj[6] = b1.z; bj[7] = b1.w;
    }

    const int s0 = gstart[g], s1 = gstart[g + 1];
    float hacc[8];
#pragma unroll
    for (int j = 0; j < 8; j++) hacc[j] = 0.f;

    for (int n = s0 + w; n < s1; n += 4) {
        int e0 = edge_start[n], e1 = edge_start[n + 1];
        float racc[8];
#pragma unroll
        for (int j = 0; j < 8; j++) racc[j] = 0.f;
        for (int e = e0; e < e1; ++e) {
            int s = csr_src[e];
            float4 r = ((const float4*)(G + (size_t)s * HID))[lane];
            const bf16x2* p = (const bf16x2*)&r;
#pragma unroll
            for (int qq = 0; qq < 4; qq++) {
                float2 f = __bfloat1622float2(p[qq]);
                racc[2 * qq] += f.x; racc[2 * qq + 1] += f.y;
            }
        }
#pragma unroll
        for (int j = 0; j < 8; j++) {
            float v = racc[j] + bj[j];
            hacc[j] += (v > 0.f ? v : 0.f);
        }
    }

    // LDS reduce 4 partial rows (epilogue cost negligible vs gather traffic)
    ((float4*)&red[w][lane * 8])[0] = make_float4(hacc[0], hacc[1], hacc[2], hacc[3]);
    ((float4*)&red[w][lane * 8])[1] = make_float4(hacc[4], hacc[5], hacc[6], hacc[7]);
    __syncthreads();
#pragma unroll
    for (int c = tid; c < HID; c += 256) {
        hg[(size_t)g * HID + c] = red[0][c] + red[1][c] + red[2][c] + red[3][c];
    }
}

// xinb[g, c] (bf16, stride 768) = c<512: hg/cnt | c<712: desc | else 0  (UNIFIED)
__global__ __launch_bounds__(256)
void build_xin_kernel(const float* __restrict__ hg, const int* __restrict__ gstart,
                      const void* __restrict__ desc_, bf16* __restrict__ xinb,
                      const int* __restrict__ flag)
{
    int idx = blockIdx.x * 256 + threadIdx.x;
    if (idx >= N_GRAPHS * XIN_PAD) return;
    int g = idx / XIN_PAD;
    int c = idx - g * XIN_PAD;
    float v;
    if (c < HID) {
        float cnt = (float)(gstart[g + 1] - gstart[g]);
        v = hg[(size_t)g * HID + c] / (cnt > 1.0f ? cnt : 1.0f);
    } else if (c < XIN_DIM) {
        size_t di = (size_t)g * N_DESC + (c - HID);
        v = (*flag == 0) ? ((const float*)desc_)[di]
                         : __bfloat162float(((const bf16*)desc_)[di]);
    } else {
        v = 0.f;
    }
    xinb[idx] = __float2bfloat16(v);
}

// out[g, c] = x2b[g,:100] @ cw[:,c] + cb[c]  (UNIFIED; out dtype by flag)
__global__ __launch_bounds__(256)
void final_layer_kernel(const bf16* __restrict__ x2b, const void* __restrict__ cw_,
                        const void* __restrict__ cb_, void* __restrict__ out_,
                        const int* __restrict__ flag)
{
    int i = blockIdx.x * 256 + threadIdx.x;
    if (i >= N_GRAPHS * N_CLASSES) return;
    int r = i >> 1, c = i & 1;
    const bf16* x = x2b + (size_t)r * HID;   // stride 512, cols 0..99 valid
    if (*flag == 0) {
        const float* cw = (const float*)cw_;
        float acc = ((const float*)cb_)[c];
#pragma unroll 4
        for (int k = 0; k < MLP2_OUT; k++)
            acc += __bfloat162float(x[k]) * cw[k * N_CLASSES + c];
        ((float*)out_)[i] = acc;
    } else {
        const bf16* cw = (const bf16*)cw_;
        float acc = __bfloat162float(((const bf16*)cb_)[c]);
#pragma unroll 4
        for (int k = 0; k < MLP2_OUT; k++)
            acc += __bfloat162float(x[k]) * __bfloat162float(cw[k * N_CLASSES + c]);
        ((bf16*)out_)[i] = __float2bfloat16(acc);
    }
}

// ---------------------------------------------------------------------------
static inline size_t align_up(size_t x, size_t a) { return (x + a - 1) & ~(a - 1); }
static inline int swgrid(int nrt, int nct) { return ((nrt + 7) / 8) * 8 * nct; }

extern "C" void kernel_launch(void* const* d_in, const int* in_sizes, int n_in,
                              void* d_out, int out_size, void* d_ws, size_t ws_size,
                              hipStream_t stream)
{
    const void* features    = d_in[0];
    const void* descriptors = d_in[1];
    const int*  src         = (const int*)d_in[2];
    const int*  dst         = (const int*)d_in[3];
    const int*  node2graph  = (const int*)d_in[4];
    const void* W1          = d_in[5];
    const void* b1          = d_in[6];
    const void* W2          = d_in[7];
    const void* b2          = d_in[8];
    const void* lw1         = d_in[9];
    const void* lb1         = d_in[10];
    const void* lw2         = d_in[11];
    const void* lb2         = d_in[12];
    const void* cw          = d_in[13];
    const void* cb          = d_in[14];
    (void)in_sizes; (void)n_in; (void)out_size; (void)ws_size;

    // ---- Workspace layout (fixed ~218 MB; proven ws >= ~239 MB) ----
    // R_A (102.4 MB): agg1 bf16 [100000,128] -> G bf16 [100000,512] (=h1@W2)
    //                 -> head buffers (xinb @0, x1b @8MB, x2b @16MB)
    // R_B (102.4 MB): h1 bf16 [100000,512]
    char* ws = (char*)d_ws;
    size_t off = 0;
    bf16* agg1 = (bf16*)(ws + off);
    bf16* G    = (bf16*)(ws + off);   // layer-2 pre-bias product h1@W2
    bf16* xinb = (bf16*)(ws + off);
    bf16* x1b  = (bf16*)(ws + off + (size_t)8 * 1024 * 1024);
    bf16* x2b  = (bf16*)(ws + off + (size_t)16 * 1024 * 1024);
    off = align_up(off + (size_t)N_NODES * HID * sizeof(bf16), 256);   // 102.4 MB
    bf16* h1 = (bf16*)(ws + off);
    off = align_up(off + (size_t)N_NODES * HID * sizeof(bf16), 256);   // +102.4 MB
    float* hg = (float*)(ws + off);
    off = align_up(off + (size_t)N_GRAPHS * HID * sizeof(float), 256); // +8.19 MB
    int* dflag = (int*)(ws + off);          off = align_up(off + 256, 256);
    int* edge_start = (int*)(ws + off);     off = align_up(off + (N_NODES + 1) * 4, 256);
    int* cursor = (int*)(ws + off);         off = align_up(off + N_NODES * 4, 256);
    int* csr_src = (int*)(ws + off);        off = align_up(off + N_EDGES * 4, 256);
    int* part = (int*)(ws + off);           off = align_up(off + NCHK * 4, 256);
    int* deg = (int*)(ws + off);            off = align_up(off + N_NODES * 4, 256);
    int* gstart = (int*)(ws + off);         off = align_up(off + (N_GRAPHS + 1) * 4, 256);
    short* W1t  = (short*)(ws + off);       off = align_up(off + (size_t)HID * IN_DIM * 2, 256);
    short* W2t  = (short*)(ws + off);       off = align_up(off + (size_t)HID * HID * 2, 256);
    short* lw1t = (short*)(ws + off);       off = align_up(off + (size_t)512 * XIN_PAD * 2, 256);
    short* lw2t = (short*)(ws + off);       off = align_up(off + (size_t)128 * HID * 2, 256);
    float* b1f  = (float*)(ws + off);       off = align_up(off + 512 * 4, 256);
    float* b2f  = (float*)(ws + off);       off = align_up(off + 512 * 4, 256);
    float* lb1f = (float*)(ws + off);       off = align_up(off + 512 * 4, 256);
    float* lb2f = (float*)(ws + off);       off = align_up(off + 128 * 4, 256);

    // ---- Detect float-tensor dtype (flag: 0=fp32, 1=bf16) ----
    detect_dtype_kernel<<<1, 256, 0, stream>>>(
        (const unsigned*)features, (unsigned)(N_NODES * IN_DIM / 2), dflag);

    // ---- Weight prep (single unified launch) ----
    {
        int nblk = (788096 + 255) / 256;
        prep_weights_kernel<<<nblk, 256, 0, stream>>>(
            W1, W2, lw1, lw2, b1, b2, lb1, lb2,
            W1t, W2t, lw1t, lw2t, b1f, b2f, lb1f, lb2f, dflag);
    }

    // ---- CSR build (counting sort by dst) + graph ranges ----
    hipMemsetAsync(deg, 0, N_NODES * 4, stream);
    deg_kernel<<<(N_EDGES + 255) / 256, 256, 0, stream>>>(dst, deg);
    scan_partial_kernel<<<NCHK, 256, 0, stream>>>(deg, part);
    scan_parts_kernel<<<1, 1, 0, stream>>>(part, edge_start);
    scan_final_kernel<<<NCHK, 256, 0, stream>>>(deg, part, edge_start, cursor);
    fill_kernel<<<(N_EDGES + 255) / 256, 256, 0, stream>>>(src, dst, cursor, csr_src);
    gstart_kernel<<<(N_NODES + 256) / 256, 256, 0, stream>>>(node2graph, gstart);

    // ---- Layer 1: gather -> agg1 (bf16), MFMA GEMM (bias+relu) -> h1 ----
    gather_feat_kernel<<<N_NODES / 4, 256, 0, stream>>>(
        features, edge_start, csr_src, agg1, dflag);
    {
        int nrt = (N_NODES + 127) / 128;   // 782 row-tiles -> 391 pairs
        int np  = (nrt + 1) / 2;
        mfma_gemm_kernel<4, 1, 2><<<swgrid(np, 4), 256, 0, stream>>>(
            (const short*)agg1, W1t, b1f, h1, N_NODES, IN_DIM, nrt);
    }

    // ---- Layer 2 (reassociated, matches reference order):
    //      G = h1 @ W2 (no bias/relu), then fused gather+bias+relu+pool ----
    {
        int nrt = (N_NODES + 127) / 128;
        int np  = (nrt + 1) / 2;
        mfma_gemm_kernel<4, 0, 2><<<swgrid(np, 4), 256, 0, stream>>>(
            (const short*)h1, W2t, b2f /*unused*/, G, N_NODES, HID, nrt);
    }
    gather_pool_kernel<<<N_GRAPHS, 256, 0, stream>>>(
        G, edge_start, csr_src, gstart, b2f, hg);

    // ---- Head (all MFMA; padded-K chaining; NRPB=1, grids already small) ----
    {
        int nthr = (N_GRAPHS * XIN_PAD + 255) / 256;
        build_xin_kernel<<<nthr, 256, 0, stream>>>(
            hg, gstart, descriptors, xinb, dflag);
    }
    {   // x1b[4000,512] = relu(xinb[4000,768] @ lw1t^T + lb1f)
        int nrt = (N_GRAPHS + 127) / 128;  // 32
        mfma_gemm_kernel<4, 1, 1><<<swgrid(nrt, 4), 256, 0, stream>>>(
            (const short*)xinb, lw1t, lb1f, x1b, N_GRAPHS, XIN_PAD, nrt);
    }
    {   // x2b cols 0..127 (stride 512) = relu(x1b @ lw2t^T + lb2f)
        int nrt = (N_GRAPHS + 127) / 128;
        mfma_gemm_kernel<1, 1, 1><<<swgrid(nrt, 1), 256, 0, stream>>>(
            (const short*)x1b, lw2t, lb2f, x2b, N_GRAPHS, HID, nrt);
    }
    {
        int nthr = (N_GRAPHS * N_CLASSES + 255) / 256;
        final_layer_kernel<<<nthr, 256, 0, stream>>>(
            x2b, cw, cb, d_out, dflag);
    }
}

// Round 12
// 425.435 us; speedup vs baseline: 1.0339x; 1.0230x over previous
//
#include <hip/hip_runtime.h>
#include <hip/hip_bf16.h>

// Problem constants (from reference)
#define N_NODES  100000
#define N_EDGES  400000
#define N_GRAPHS 4000
#define IN_DIM   128
#define HID      512
#define N_DESC   200
#define N_CLASSES 2
#define MLP1_OUT 500
#define MLP2_OUT 100
#define XIN_DIM  (HID + N_DESC)   // 712
#define XIN_PAD  768              // K padded to multiple of 64

#define SCAN_CHUNK 1024
#define NCHK ((N_NODES + SCAN_CHUNK - 1) / SCAN_CHUNK)   // 98
#define DEG_BLKS ((N_EDGES + 255) / 256)                 // 1563

typedef __hip_bfloat16  bf16;
typedef __hip_bfloat162 bf16x2;
typedef short s8v  __attribute__((ext_vector_type(8)));   // 8 bf16 (4 VGPRs)
typedef float f32x4 __attribute__((ext_vector_type(4)));

// ---------------------------------------------------------------------------
// Dtype-generic helpers (FT = float or bf16), all produce fp32.
// ---------------------------------------------------------------------------
__device__ __forceinline__ float ldf(const float* p, size_t i) { return p[i]; }
__device__ __forceinline__ float ldf(const bf16* p, size_t i)  { return __bfloat162float(p[i]); }

__device__ __forceinline__ short f2bs(float x) {
    bf16 h = __float2bfloat16(x);
    return __builtin_bit_cast(short, h);
}

// async global->LDS, 16B per lane; LDS dest = wave-uniform base + lane*16
__device__ __forceinline__ void gld16(const short* g, short* l) {
    __builtin_amdgcn_global_load_lds(
        (const __attribute__((address_space(1))) unsigned int*)g,
        (__attribute__((address_space(3))) unsigned int*)l, 16, 0, 0);
}

#define MEMFENCE asm volatile("" ::: "memory")

// ---------------------------------------------------------------------------
// Runtime dtype detection (flag: 0=fp32, 1=bf16)
// ---------------------------------------------------------------------------
__global__ __launch_bounds__(256)
void detect_dtype_kernel(const unsigned* __restrict__ words, unsigned nw,
                         int* __restrict__ flag)
{
    __shared__ int s_cnt;
    if (threadIdx.x == 0) s_cnt = 0;
    __syncthreads();
    const int SAMPLES = 2048;
    int sane = 0;
    for (int i = threadIdx.x; i < SAMPLES; i += 256) {
        size_t idx = (size_t)(((unsigned long long)i * 2654435761ull) % nw);
        unsigned w = words[idx];
        float f = __uint_as_float((w & 0xFFFFu) << 16);
        float a = fabsf(f);
        if (f == 0.0f || (a > 1e-8f && a < 1e8f)) sane++;
    }
    atomicAdd(&s_cnt, sane);
    __syncthreads();
    if (threadIdx.x == 0) *flag = (s_cnt * 10 > SAMPLES * 6) ? 1 : 0;
}

// ---------------------------------------------------------------------------
// Fused weight prep (UNIFIED: runtime dtype branch): weights -> transposed
// bf16 [N][K] (zero-pad), biases -> fp32 (zero-pad). Segments: W1t 65536 |
// W2t 262144 | lw1t 393216 | lw2t 65536 | b1f 512 | b2f 512 | lb1f 512 |
// lb2f 128  (total 788096)
// ---------------------------------------------------------------------------
template<typename FT>
__device__ __forceinline__
void prep_body(int i, const FT* W1, const FT* W2, const FT* lw1, const FT* lw2,
               const FT* b1, const FT* b2, const FT* lb1, const FT* lb2,
               short* W1t, short* W2t, short* lw1t, short* lw2t,
               float* b1f, float* b2f, float* lb1f, float* lb2f)
{
    if (i < 65536) {            // W1t [512][128] <- W1 [128,512]
        int n = i >> 7, k = i & 127;
        W1t[i] = f2bs(ldf(W1, (size_t)k * HID + n));
        return;
    }
    i -= 65536;
    if (i < 262144) {           // W2t [512][512] <- W2 [512,512]
        int n = i >> 9, k = i & 511;
        W2t[i] = f2bs(ldf(W2, (size_t)k * HID + n));
        return;
    }
    i -= 262144;
    if (i < 393216) {           // lw1t [512][768] <- lw1 [712,500], zero-pad
        int n = i / XIN_PAD, k = i - n * XIN_PAD;
        lw1t[i] = (n < MLP1_OUT && k < XIN_DIM)
                      ? f2bs(ldf(lw1, (size_t)k * MLP1_OUT + n)) : (short)0;
        return;
    }
    i -= 393216;
    if (i < 65536) {            // lw2t [128][512] <- lw2 [500,100], zero-pad
        int n = i >> 9, k = i & 511;
        lw2t[i] = (n < MLP2_OUT && k < MLP1_OUT)
                      ? f2bs(ldf(lw2, (size_t)k * MLP2_OUT + n)) : (short)0;
        return;
    }
    i -= 65536;
    if (i < 512) { b1f[i] = ldf(b1, i); return; }
    i -= 512;
    if (i < 512) { b2f[i] = ldf(b2, i); return; }
    i -= 512;
    if (i < 512) { lb1f[i] = (i < MLP1_OUT) ? ldf(lb1, i) : 0.f; return; }
    i -= 512;
    if (i < 128) { lb2f[i] = (i < MLP2_OUT) ? ldf(lb2, i) : 0.f; return; }
}

__global__ __launch_bounds__(256)
void prep_weights_kernel(const void* __restrict__ W1, const void* __restrict__ W2,
                         const void* __restrict__ lw1, const void* __restrict__ lw2,
                         const void* __restrict__ b1, const void* __restrict__ b2,
                         const void* __restrict__ lb1, const void* __restrict__ lb2,
                         short* __restrict__ W1t, short* __restrict__ W2t,
                         short* __restrict__ lw1t, short* __restrict__ lw2t,
                         float* __restrict__ b1f, float* __restrict__ b2f,
                         float* __restrict__ lb1f, float* __restrict__ lb2f,
                         const int* __restrict__ flag)
{
    int i = blockIdx.x * 256 + threadIdx.x;
    if (*flag == 0)
        prep_body<float>(i, (const float*)W1, (const float*)W2, (const float*)lw1,
                         (const float*)lw2, (const float*)b1, (const float*)b2,
                         (const float*)lb1, (const float*)lb2,
                         W1t, W2t, lw1t, lw2t, b1f, b2f, lb1f, lb2f);
    else
        prep_body<bf16>(i, (const bf16*)W1, (const bf16*)W2, (const bf16*)lw1,
                        (const bf16*)lw2, (const bf16*)b1, (const bf16*)b2,
                        (const bf16*)lb1, (const bf16*)lb2,
                        W1t, W2t, lw1t, lw2t, b1f, b2f, lb1f, lb2f);
}

// ---------------------------------------------------------------------------
// CSR build: deg histogram (+ fused gstart) -> two-level scan -> fill
// ---------------------------------------------------------------------------
// Fused: blocks [0, DEG_BLKS) do the degree histogram; blocks [DEG_BLKS, ...)
// compute gstart (independent input n2g -> safe to fuse; saves a dispatch).
__global__ __launch_bounds__(256)
void deg_gstart_kernel(const int* __restrict__ dst, int* __restrict__ deg,
                       const int* __restrict__ n2g, int* __restrict__ gstart)
{
    int b = blockIdx.x;
    int t = threadIdx.x;
    if (b < DEG_BLKS) {
        int e = b * 256 + t;
        if (e < N_EDGES) atomicAdd(&deg[dst[e]], 1);
        return;
    }
    int n = (b - DEG_BLKS) * 256 + t;
    if (n > N_NODES) return;
    if (n == N_NODES) {
        int last = n2g[N_NODES - 1];
        for (int g = last + 1; g <= N_GRAPHS; g++) gstart[g] = N_NODES;
        return;
    }
    int v = n2g[n];
    int prev = (n == 0) ? -1 : n2g[n - 1];
    for (int g = prev + 1; g <= v; g++) gstart[g] = n;
}

__global__ __launch_bounds__(256)
void scan_partial_kernel(const int* __restrict__ deg, int* __restrict__ part)
{
    int c = blockIdx.x, t = threadIdx.x;
    int i0 = c * SCAN_CHUNK + t * 4;
    int s = 0;
#pragma unroll
    for (int j = 0; j < 4; j++) {
        int i = i0 + j;
        if (i < N_NODES) s += deg[i];
    }
    __shared__ int red[256];
    red[t] = s;
    __syncthreads();
    for (int off = 128; off > 0; off >>= 1) {
        if (t < off) red[t] += red[t + off];
        __syncthreads();
    }
    if (t == 0) part[c] = red[0];
}

__global__ void scan_parts_kernel(int* __restrict__ part, int* __restrict__ edge_start)
{
    int run = 0;
    for (int c = 0; c < NCHK; c++) { int v = part[c]; part[c] = run; run += v; }
    edge_start[N_NODES] = run;
}

// also initializes cursor[] (saves a dispatch)
__global__ __launch_bounds__(256)
void scan_final_kernel(const int* __restrict__ deg, const int* __restrict__ part,
                       int* __restrict__ edge_start, int* __restrict__ cursor)
{
    int c = blockIdx.x, t = threadIdx.x;
    int i0 = c * SCAN_CHUNK + t * 4;
    int d[4];
    int tsum = 0;
#pragma unroll
    for (int j = 0; j < 4; j++) {
        int i = i0 + j;
        d[j] = (i < N_NODES) ? deg[i] : 0;
        tsum += d[j];
    }
    __shared__ int s[256];
    s[t] = tsum;
    __syncthreads();
    for (int off = 1; off < 256; off <<= 1) {
        int v = (t >= off) ? s[t - off] : 0;
        __syncthreads();
        s[t] += v;
        __syncthreads();
    }
    int run = part[c] + s[t] - tsum;
#pragma unroll
    for (int j = 0; j < 4; j++) {
        int i = i0 + j;
        if (i < N_NODES) { edge_start[i] = run; cursor[i] = run; run += d[j]; }
    }
}

__global__ __launch_bounds__(256)
void fill_kernel(const int* __restrict__ src, const int* __restrict__ dst,
                 int* __restrict__ cursor, int* __restrict__ csr_src)
{
    int e = blockIdx.x * 256 + threadIdx.x;
    if (e >= N_EDGES) return;
    int p = atomicAdd(&cursor[dst[e]], 1);
    csr_src[p] = src[e];
}

// ---------------------------------------------------------------------------
// Layer-1 gather (UNIFIED): agg1[n,0:128] = sum_{e: dst=n} feat[src[e],0:128]
// ---------------------------------------------------------------------------
__global__ __launch_bounds__(256)
void gather_feat_kernel(const void* __restrict__ feat_, const int* __restrict__ edge_start,
                        const int* __restrict__ csr_src, bf16* __restrict__ agg1,
                        const int* __restrict__ flag)
{
    int n = blockIdx.x * 4 + (threadIdx.x >> 6);
    if (n >= N_NODES) return;
    int lane = threadIdx.x & 63;
    int e0 = edge_start[n], e1 = edge_start[n + 1];
    float2 acc = {0.f, 0.f};
    if (*flag == 0) {
        const float* feat = (const float*)feat_;
        for (int i = e0; i < e1; i++) {
            int s = csr_src[i];
            float2 f = ((const float2*)(feat + (size_t)s * IN_DIM))[lane];
            acc.x += f.x; acc.y += f.y;
        }
    } else {
        const bf16* feat = (const bf16*)feat_;
        for (int i = e0; i < e1; i++) {
            int s = csr_src[i];
            float2 f = __bfloat1622float2(((const bf16x2*)(feat + (size_t)s * IN_DIM))[lane]);
            acc.x += f.x; acc.y += f.y;
        }
    }
    bf16x2 p;
    p.x = __float2bfloat16(acc.x);
    p.y = __float2bfloat16(acc.y);
    ((bf16x2*)(agg1 + (size_t)n * IN_DIM))[lane] = p;
}

// ---------------------------------------------------------------------------
// MFMA bf16 GEMM — BK=32, THREE-buffer rotation, prefetch depth 2, counted
// vmcnt (T4), register diet, __launch_bounds__(256,4).
// Round-12 rationale: round-11 falsified per-block fixed cost (NRPB=2 null)
// AND exposed that "K-independence" compared GEMM2 with itself (all top-5
// FETCH~53MB = GEMM2 signature). With depth-1 prefetch each K-iter exposes
// the staging latency; depth-2 keeps 8 loads in flight across two future
// tiles: steady-state s_waitcnt vmcnt(8), tails vmcnt(4)/vmcnt(0).
// LDS 3 x 8192 shorts = 48 KB (cap 3 blocks/CU >= measured 2.4 effective);
// epilogue Cs (17408 shorts) aliases buffers after the final barrier.
// Hazard: stage at iter t+1 overwrites buf[t%3]; all reads of buf[t%3]
// completed before iter t's closing barrier -> safe.
//   ACT=1: C = relu(A @ Bt^T + bias); ACT=0: C = A @ Bt^T.
// ---------------------------------------------------------------------------
template<int NCT, int ACT>
__global__ __launch_bounds__(256, 4)
void mfma_gemm_kernel(const short* __restrict__ A, const short* __restrict__ Bt,
                      const float* __restrict__ biasf, bf16* __restrict__ Cout,
                      int M, int K, int nrt)
{
    __shared__ short smem[24576];   // 3 bufs x 8192 shorts = 48 KB
    short* Cs = smem;               // epilogue alias

    // XCD-colocating decode
    const int b  = blockIdx.x;
    const int r8 = b & 7;
    const int t0 = b >> 3;
    const int x  = (t0 / NCT) * 8 + r8;
    const int y  = t0 % NCT;
    if (x >= nrt) return;
    const int row0 = x * 128;
    const int col0 = y * 128;

    const int tid  = threadIdx.x;
    const int lane = tid & 63;
    const int w    = tid >> 6;
    const int wr = w >> 1, wc = w & 1;
    const int m  = lane & 15, q = lane >> 4;

    // Staging (BK=32): per wave 2 A-chunks + 2 B-chunks (1 KB each).
    const int rr = lane >> 2;
    const int dc = ((lane & 3) ^ ((lane >> 3) & 3)) * 8;
    const short* pA = A  + (size_t)(row0 + w * 32 + rr) * K + dc;  // OOB: in-ws garbage
    const short* pB = Bt + (size_t)(col0 + w * 32 + rr) * K + dc;  // Bt padded
    const int cOff = 16 * K;            // chunk-1 row offset (wave-uniform)

    // Fragment-read swizzled slot offset (shorts): row m, granule q
    const int so = (q ^ ((m >> 1) & 3)) * 8;

    f32x4 acc[4][4];
#pragma unroll
    for (int i = 0; i < 4; i++)
#pragma unroll
        for (int j = 0; j < 4; j++) acc[i][j] = {0.f, 0.f, 0.f, 0.f};

    // Prologue: stage tile 0 -> buf0, tile 1 -> buf1 (NT >= 4 always; 8 loads
    // outstanding per wave)
    {
        short* d = smem + w * 1024;
        gld16(pA, d);               gld16(pA + cOff, d + 512);
        gld16(pB, d + 4096);        gld16(pB + cOff, d + 4096 + 512);
        pA += 32; pB += 32;
        d = smem + 8192 + w * 1024;
        gld16(pA, d);               gld16(pA + cOff, d + 512);
        gld16(pB, d + 4096);        gld16(pB + cOff, d + 4096 + 512);
        pA += 32; pB += 32;
    }

    const int NT = K >> 5;
    int bc = 0;                         // compute-buffer offset (shorts)
    for (int t = 0; t < NT; ++t) {
        if (t + 2 < NT) {
            int bs2 = bc + 16384;       // buffer two ahead (mod 3)
            if (bs2 >= 24576) bs2 -= 24576;
            short* d = smem + bs2 + w * 1024;
            gld16(pA, d);           gld16(pA + cOff, d + 512);
            gld16(pB, d + 4096);    gld16(pB + cOff, d + 4096 + 512);
            pA += 32; pB += 32;
            // tiles t+1, t+2 in flight (8 loads); tile t landed
            asm volatile("s_waitcnt vmcnt(8)" ::: "memory");
        } else if (t + 2 == NT) {
            asm volatile("s_waitcnt vmcnt(4)" ::: "memory");
        } else {
            asm volatile("s_waitcnt vmcnt(0)" ::: "memory");
        }
        __builtin_amdgcn_s_barrier();   // raw: no implicit vmcnt(0) drain
        MEMFENCE;

        const short* Ab = smem + bc;
        const short* Bb = smem + bc + 4096;
        s8v av[4], bv[4];
#pragma unroll
        for (int rt = 0; rt < 4; rt++)
            av[rt] = *(const s8v*)&Ab[(wr * 64 + rt * 16 + m) * 32 + so];
#pragma unroll
        for (int ct = 0; ct < 4; ct++)
            bv[ct] = *(const s8v*)&Bb[(wc * 64 + ct * 16 + m) * 32 + so];
#pragma unroll
        for (int rt = 0; rt < 4; rt++)
#pragma unroll
            for (int ct = 0; ct < 4; ct++)
                acc[rt][ct] = __builtin_amdgcn_mfma_f32_16x16x32_bf16(
                    av[rt], bv[ct], acc[rt][ct], 0, 0, 0);

        MEMFENCE;
        __builtin_amdgcn_s_barrier();   // buf bc free for reuse at next stage
        MEMFENCE;
        bc = (bc == 16384) ? 0 : bc + 8192;
    }

    // Epilogue phase 1: (ACT: bias + relu) -> bf16 C-tile into LDS (pad-136)
#pragma unroll
    for (int rt = 0; rt < 4; rt++) {
#pragma unroll
        for (int ct = 0; ct < 4; ct++) {
            int lcol = wc * 64 + ct * 16 + m;
            float bv = ACT ? biasf[col0 + lcol] : 0.f;
#pragma unroll
            for (int reg = 0; reg < 4; reg++) {
                int lrow = wr * 64 + rt * 16 + q * 4 + reg;
                float v = acc[rt][ct][reg];
                if constexpr (ACT) {
                    v += bv;
                    v = v > 0.f ? v : 0.f;
                }
                Cs[lrow * 136 + lcol] = f2bs(v);
            }
        }
    }
    __syncthreads();

    // Epilogue phase 2: coalesced 16B stores (wave = 4 full 256B row segments)
#pragma unroll
    for (int it = 0; it < 8; it++) {
        int idx = it * 256 + tid;
        int r = idx >> 4;
        int c = (idx & 15) * 8;
        int row = row0 + r;
        if (row < M)
            *(float4*)&Cout[(size_t)row * HID + col0 + c] =
                *(const float4*)&Cs[r * 136 + c];
    }
}

// ---------------------------------------------------------------------------
// FUSED layer-2 gather + bias + relu + graph mean-pool numerator, NO atomics.
// Round-9 geometry: block (4 waves) per graph, wave w strides nodes by 4,
// register accumulate, 8KB LDS reduction + one coalesced hg write.
//   hg[g,:] = sum_n relu( sum_{e: dst=n} G[csr_src[e],:] + b2 ),  G = h1@W2
// ---------------------------------------------------------------------------
__global__ __launch_bounds__(256)
void gather_pool_kernel(const bf16* __restrict__ G, const int* __restrict__ edge_start,
                        const int* __restrict__ csr_src, const int* __restrict__ gstart,
                        const float* __restrict__ b2f, float* __restrict__ hg)
{
    __shared__ float red[4][HID];
    const int g = blockIdx.x;
    const int tid = threadIdx.x;
    const int lane = tid & 63;
    const int w = tid >> 6;

    float bj[8];
    {
        const float4* bp = (const float4*)(b2f + lane * 8);
        float4 b0 = bp[0], b1 = bp[1];
        bj[0] = b0.x; bj[1] = b0.y; bj[2] = b0.z; bj[3] = b0.w;
        bj[4] = b1.x; bj[5] = b1.y; bj[6] = b1.z; bj[7] = b1.w;
    }

    const int s0 = gstart[g], s1 = gstart[g + 1];
    float hacc[8];
#pragma unroll
    for (int j = 0; j < 8; j++) hacc[j] = 0.f;

    for (int n = s0 + w; n < s1; n += 4) {
        int e0 = edge_start[n], e1 = edge_start[n + 1];
        float racc[8];
#pragma unroll
        for (int j = 0; j < 8; j++) racc[j] = 0.f;
        for (int e = e0; e < e1; ++e) {
            int s = csr_src[e];
            float4 r = ((const float4*)(G + (size_t)s * HID))[lane];
            const bf16x2* p = (const bf16x2*)&r;
#pragma unroll
            for (int qq = 0; qq < 4; qq++) {
                float2 f = __bfloat1622float2(p[qq]);
                racc[2 * qq] += f.x; racc[2 * qq + 1] += f.y;
            }
        }
#pragma unroll
        for (int j = 0; j < 8; j++) {
            float v = racc[j] + bj[j];
            hacc[j] += (v > 0.f ? v : 0.f);
        }
    }

    // LDS reduce 4 partial rows (epilogue cost negligible vs gather traffic)
    ((float4*)&red[w][lane * 8])[0] = make_float4(hacc[0], hacc[1], hacc[2], hacc[3]);
    ((float4*)&red[w][lane * 8])[1] = make_float4(hacc[4], hacc[5], hacc[6], hacc[7]);
    __syncthreads();
#pragma unroll
    for (int c = tid; c < HID; c += 256) {
        hg[(size_t)g * HID + c] = red[0][c] + red[1][c] + red[2][c] + red[3][c];
    }
}

// xinb[g, c] (bf16, stride 768) = c<512: hg/cnt | c<712: desc | else 0  (UNIFIED)
__global__ __launch_bounds__(256)
void build_xin_kernel(const float* __restrict__ hg, const int* __restrict__ gstart,
                      const void* __restrict__ desc_, bf16* __restrict__ xinb,
                      const int* __restrict__ flag)
{
    int idx = blockIdx.x * 256 + threadIdx.x;
    if (idx >= N_GRAPHS * XIN_PAD) return;
    int g = idx / XIN_PAD;
    int c = idx - g * XIN_PAD;
    float v;
    if (c < HID) {
        float cnt = (float)(gstart[g + 1] - gstart[g]);
        v = hg[(size_t)g * HID + c] / (cnt > 1.0f ? cnt : 1.0f);
    } else if (c < XIN_DIM) {
        size_t di = (size_t)g * N_DESC + (c - HID);
        v = (*flag == 0) ? ((const float*)desc_)[di]
                         : __bfloat162float(((const bf16*)desc_)[di]);
    } else {
        v = 0.f;
    }
    xinb[idx] = __float2bfloat16(v);
}

// out[g, c] = x2b[g,:100] @ cw[:,c] + cb[c]  (UNIFIED; out dtype by flag)
__global__ __launch_bounds__(256)
void final_layer_kernel(const bf16* __restrict__ x2b, const void* __restrict__ cw_,
                        const void* __restrict__ cb_, void* __restrict__ out_,
                        const int* __restrict__ flag)
{
    int i = blockIdx.x * 256 + threadIdx.x;
    if (i >= N_GRAPHS * N_CLASSES) return;
    int r = i >> 1, c = i & 1;
    const bf16* x = x2b + (size_t)r * HID;   // stride 512, cols 0..99 valid
    if (*flag == 0) {
        const float* cw = (const float*)cw_;
        float acc = ((const float*)cb_)[c];
#pragma unroll 4
        for (int k = 0; k < MLP2_OUT; k++)
            acc += __bfloat162float(x[k]) * cw[k * N_CLASSES + c];
        ((float*)out_)[i] = acc;
    } else {
        const bf16* cw = (const bf16*)cw_;
        float acc = __bfloat162float(((const bf16*)cb_)[c]);
#pragma unroll 4
        for (int k = 0; k < MLP2_OUT; k++)
            acc += __bfloat162float(x[k]) * __bfloat162float(cw[k * N_CLASSES + c]);
        ((bf16*)out_)[i] = __float2bfloat16(acc);
    }
}

// ---------------------------------------------------------------------------
static inline size_t align_up(size_t x, size_t a) { return (x + a - 1) & ~(a - 1); }
static inline int swgrid(int nrt, int nct) { return ((nrt + 7) / 8) * 8 * nct; }

extern "C" void kernel_launch(void* const* d_in, const int* in_sizes, int n_in,
                              void* d_out, int out_size, void* d_ws, size_t ws_size,
                              hipStream_t stream)
{
    const void* features    = d_in[0];
    const void* descriptors = d_in[1];
    const int*  src         = (const int*)d_in[2];
    const int*  dst         = (const int*)d_in[3];
    const int*  node2graph  = (const int*)d_in[4];
    const void* W1          = d_in[5];
    const void* b1          = d_in[6];
    const void* W2          = d_in[7];
    const void* b2          = d_in[8];
    const void* lw1         = d_in[9];
    const void* lb1         = d_in[10];
    const void* lw2         = d_in[11];
    const void* lb2         = d_in[12];
    const void* cw          = d_in[13];
    const void* cb          = d_in[14];
    (void)in_sizes; (void)n_in; (void)out_size; (void)ws_size;

    // ---- Workspace layout (fixed ~218 MB; proven ws >= ~239 MB) ----
    // R_A (102.4 MB): agg1 bf16 [100000,128] -> G bf16 [100000,512] (=h1@W2)
    //                 -> head buffers (xinb @0, x1b @8MB, x2b @16MB)
    // R_B (102.4 MB): h1 bf16 [100000,512]
    char* ws = (char*)d_ws;
    size_t off = 0;
    bf16* agg1 = (bf16*)(ws + off);
    bf16* G    = (bf16*)(ws + off);   // layer-2 pre-bias product h1@W2
    bf16* xinb = (bf16*)(ws + off);
    bf16* x1b  = (bf16*)(ws + off + (size_t)8 * 1024 * 1024);
    bf16* x2b  = (bf16*)(ws + off + (size_t)16 * 1024 * 1024);
    off = align_up(off + (size_t)N_NODES * HID * sizeof(bf16), 256);   // 102.4 MB
    bf16* h1 = (bf16*)(ws + off);
    off = align_up(off + (size_t)N_NODES * HID * sizeof(bf16), 256);   // +102.4 MB
    float* hg = (float*)(ws + off);
    off = align_up(off + (size_t)N_GRAPHS * HID * sizeof(float), 256); // +8.19 MB
    int* dflag = (int*)(ws + off);          off = align_up(off + 256, 256);
    int* edge_start = (int*)(ws + off);     off = align_up(off + (N_NODES + 1) * 4, 256);
    int* cursor = (int*)(ws + off);         off = align_up(off + N_NODES * 4, 256);
    int* csr_src = (int*)(ws + off);        off = align_up(off + N_EDGES * 4, 256);
    int* part = (int*)(ws + off);           off = align_up(off + NCHK * 4, 256);
    int* deg = (int*)(ws + off);            off = align_up(off + N_NODES * 4, 256);
    int* gstart = (int*)(ws + off);         off = align_up(off + (N_GRAPHS + 1) * 4, 256);
    short* W1t  = (short*)(ws + off);       off = align_up(off + (size_t)HID * IN_DIM * 2, 256);
    short* W2t  = (short*)(ws + off);       off = align_up(off + (size_t)HID * HID * 2, 256);
    short* lw1t = (short*)(ws + off);       off = align_up(off + (size_t)512 * XIN_PAD * 2, 256);
    short* lw2t = (short*)(ws + off);       off = align_up(off + (size_t)128 * HID * 2, 256);
    float* b1f  = (float*)(ws + off);       off = align_up(off + 512 * 4, 256);
    float* b2f  = (float*)(ws + off);       off = align_up(off + 512 * 4, 256);
    float* lb1f = (float*)(ws + off);       off = align_up(off + 512 * 4, 256);
    float* lb2f = (float*)(ws + off);       off = align_up(off + 128 * 4, 256);

    // ---- Detect float-tensor dtype (flag: 0=fp32, 1=bf16) ----
    detect_dtype_kernel<<<1, 256, 0, stream>>>(
        (const unsigned*)features, (unsigned)(N_NODES * IN_DIM / 2), dflag);

    // ---- Weight prep (single unified launch) ----
    {
        int nblk = (788096 + 255) / 256;
        prep_weights_kernel<<<nblk, 256, 0, stream>>>(
            W1, W2, lw1, lw2, b1, b2, lb1, lb2,
            W1t, W2t, lw1t, lw2t, b1f, b2f, lb1f, lb2f, dflag);
    }

    // ---- CSR build (counting sort by dst) + graph ranges ----
    hipMemsetAsync(deg, 0, N_NODES * 4, stream);
    {
        int gblk = (N_NODES + 256) / 256;          // 391 (covers n <= N_NODES)
        deg_gstart_kernel<<<DEG_BLKS + gblk, 256, 0, stream>>>(
            dst, deg, node2graph, gstart);
    }
    scan_partial_kernel<<<NCHK, 256, 0, stream>>>(deg, part);
    scan_parts_kernel<<<1, 1, 0, stream>>>(part, edge_start);
    scan_final_kernel<<<NCHK, 256, 0, stream>>>(deg, part, edge_start, cursor);
    fill_kernel<<<(N_EDGES + 255) / 256, 256, 0, stream>>>(src, dst, cursor, csr_src);

    // ---- Layer 1: gather -> agg1 (bf16), MFMA GEMM (bias+relu) -> h1 ----
    gather_feat_kernel<<<N_NODES / 4, 256, 0, stream>>>(
        features, edge_start, csr_src, agg1, dflag);
    {
        int nrt = (N_NODES + 127) / 128;   // 782
        mfma_gemm_kernel<4, 1><<<swgrid(nrt, 4), 256, 0, stream>>>(
            (const short*)agg1, W1t, b1f, h1, N_NODES, IN_DIM, nrt);
    }

    // ---- Layer 2 (reassociated, matches reference order):
    //      G = h1 @ W2 (no bias/relu), then fused gather+bias+relu+pool ----
    {
        int nrt = (N_NODES + 127) / 128;
        mfma_gemm_kernel<4, 0><<<swgrid(nrt, 4), 256, 0, stream>>>(
            (const short*)h1, W2t, b2f /*unused*/, G, N_NODES, HID, nrt);
    }
    gather_pool_kernel<<<N_GRAPHS, 256, 0, stream>>>(
        G, edge_start, csr_src, gstart, b2f, hg);

    // ---- Head (all MFMA; padded-K chaining) ----
    {
        int nthr = (N_GRAPHS * XIN_PAD + 255) / 256;
        build_xin_kernel<<<nthr, 256, 0, stream>>>(
            hg, gstart, descriptors, xinb, dflag);
    }
    {   // x1b[4000,512] = relu(xinb[4000,768] @ lw1t^T + lb1f)
        int nrt = (N_GRAPHS + 127) / 128;  // 32
        mfma_gemm_kernel<4, 1><<<swgrid(nrt, 4), 256, 0, stream>>>(
            (const short*)xinb, lw1t, lb1f, x1b, N_GRAPHS, XIN_PAD, nrt);
    }
    {   // x2b cols 0..127 (stride 512) = relu(x1b @ lw2t^T + lb2f)
        int nrt = (N_GRAPHS + 127) / 128;
        mfma_gemm_kernel<1, 1><<<swgrid(nrt, 1), 256, 0, stream>>>(
            (const short*)x1b, lw2t, lb2f, x2b, N_GRAPHS, HID, nrt);
    }
    {
        int nthr = (N_GRAPHS * N_CLASSES + 255) / 256;
        final_layer_kernel<<<nthr, 256, 0, stream>>>(
            x2b, cw, cb, d_out, dflag);
    }
}

// Round 14
// 418.297 us; speedup vs baseline: 1.0515x; 1.0171x over previous
//
#include <hip/hip_runtime.h>
#include <hip/hip_bf16.h>

// Problem constants (from reference)
#define N_NODES  100000
#define N_EDGES  400000
#define N_GRAPHS 4000
#define IN_DIM   128
#define HID      512
#define N_DESC   200
#define N_CLASSES 2
#define MLP1_OUT 500
#define MLP2_OUT 100
#define XIN_DIM  (HID + N_DESC)   // 712
#define XIN_PAD  768              // K padded to multiple of 64

#define SCAN_CHUNK 1024
#define NCHK ((N_NODES + SCAN_CHUNK - 1) / SCAN_CHUNK)   // 98
#define DEG_BLKS ((N_EDGES + 255) / 256)                 // 1563

typedef __hip_bfloat16  bf16;
typedef __hip_bfloat162 bf16x2;
typedef short s8v  __attribute__((ext_vector_type(8)));   // 8 bf16 (4 VGPRs)
typedef float f32x4 __attribute__((ext_vector_type(4)));

// ---------------------------------------------------------------------------
// Dtype-generic helpers (FT = float or bf16), all produce fp32.
// ---------------------------------------------------------------------------
__device__ __forceinline__ float ldf(const float* p, size_t i) { return p[i]; }
__device__ __forceinline__ float ldf(const bf16* p, size_t i)  { return __bfloat162float(p[i]); }

__device__ __forceinline__ short f2bs(float x) {
    bf16 h = __float2bfloat16(x);
    return __builtin_bit_cast(short, h);
}

__device__ __forceinline__ float bs2f(short s) {
    return __bfloat162float(__builtin_bit_cast(bf16, s));
}

// async global->LDS, 16B per lane; LDS dest = wave-uniform base + lane*16
__device__ __forceinline__ void gld16(const short* g, short* l) {
    __builtin_amdgcn_global_load_lds(
        (const __attribute__((address_space(1))) unsigned int*)g,
        (__attribute__((address_space(3))) unsigned int*)l, 16, 0, 0);
}

#define MEMFENCE asm volatile("" ::: "memory")

// ---------------------------------------------------------------------------
// Runtime dtype detection (flag: 0=fp32, 1=bf16)
// ---------------------------------------------------------------------------
__global__ __launch_bounds__(256)
void detect_dtype_kernel(const unsigned* __restrict__ words, unsigned nw,
                         int* __restrict__ flag)
{
    __shared__ int s_cnt;
    if (threadIdx.x == 0) s_cnt = 0;
    __syncthreads();
    const int SAMPLES = 2048;
    int sane = 0;
    for (int i = threadIdx.x; i < SAMPLES; i += 256) {
        size_t idx = (size_t)(((unsigned long long)i * 2654435761ull) % nw);
        unsigned w = words[idx];
        float f = __uint_as_float((w & 0xFFFFu) << 16);
        float a = fabsf(f);
        if (f == 0.0f || (a > 1e-8f && a < 1e8f)) sane++;
    }
    atomicAdd(&s_cnt, sane);
    __syncthreads();
    if (threadIdx.x == 0) *flag = (s_cnt * 10 > SAMPLES * 6) ? 1 : 0;
}

// ---------------------------------------------------------------------------
// Fused weight prep (UNIFIED): weights -> transposed bf16 [N][K] (zero-pad),
// biases -> fp32. Segments: W1t 65536 | W2t 262144 | lw1t 393216 |
// lw2t 65536 | b1f 512 | b2f 512 | lb1f 512 | lb2f 128 | cwf 256 | cbf 64
// (total 788416). cwf/cbf: classifier weights as fp32 for the fused FINAL
// epilogue (value-path identical to the old per-use convert).
// ---------------------------------------------------------------------------
template<typename FT>
__device__ __forceinline__
void prep_body(int i, const FT* W1, const FT* W2, const FT* lw1, const FT* lw2,
               const FT* b1, const FT* b2, const FT* lb1, const FT* lb2,
               const FT* cw, const FT* cb,
               short* W1t, short* W2t, short* lw1t, short* lw2t,
               float* b1f, float* b2f, float* lb1f, float* lb2f,
               float* cwf, float* cbf)
{
    if (i < 65536) {            // W1t [512][128] <- W1 [128,512]
        int n = i >> 7, k = i & 127;
        W1t[i] = f2bs(ldf(W1, (size_t)k * HID + n));
        return;
    }
    i -= 65536;
    if (i < 262144) {           // W2t [512][512] <- W2 [512,512]
        int n = i >> 9, k = i & 511;
        W2t[i] = f2bs(ldf(W2, (size_t)k * HID + n));
        return;
    }
    i -= 262144;
    if (i < 393216) {           // lw1t [512][768] <- lw1 [712,500], zero-pad
        int n = i / XIN_PAD, k = i - n * XIN_PAD;
        lw1t[i] = (n < MLP1_OUT && k < XIN_DIM)
                      ? f2bs(ldf(lw1, (size_t)k * MLP1_OUT + n)) : (short)0;
        return;
    }
    i -= 393216;
    if (i < 65536) {            // lw2t [128][512] <- lw2 [500,100], zero-pad
        int n = i >> 9, k = i & 511;
        lw2t[i] = (n < MLP2_OUT && k < MLP1_OUT)
                      ? f2bs(ldf(lw2, (size_t)k * MLP2_OUT + n)) : (short)0;
        return;
    }
    i -= 65536;
    if (i < 512) { b1f[i] = ldf(b1, i); return; }
    i -= 512;
    if (i < 512) { b2f[i] = ldf(b2, i); return; }
    i -= 512;
    if (i < 512) { lb1f[i] = (i < MLP1_OUT) ? ldf(lb1, i) : 0.f; return; }
    i -= 512;
    if (i < 128) { lb2f[i] = (i < MLP2_OUT) ? ldf(lb2, i) : 0.f; return; }
    i -= 128;
    if (i < 256) { cwf[i] = (i < MLP2_OUT * N_CLASSES) ? ldf(cw, i) : 0.f; return; }
    i -= 256;
    if (i < 64)  { cbf[i] = (i < N_CLASSES) ? ldf(cb, i) : 0.f; return; }
}

__global__ __launch_bounds__(256)
void prep_weights_kernel(const void* __restrict__ W1, const void* __restrict__ W2,
                         const void* __restrict__ lw1, const void* __restrict__ lw2,
                         const void* __restrict__ b1, const void* __restrict__ b2,
                         const void* __restrict__ lb1, const void* __restrict__ lb2,
                         const void* __restrict__ cw, const void* __restrict__ cb,
                         short* __restrict__ W1t, short* __restrict__ W2t,
                         short* __restrict__ lw1t, short* __restrict__ lw2t,
                         float* __restrict__ b1f, float* __restrict__ b2f,
                         float* __restrict__ lb1f, float* __restrict__ lb2f,
                         float* __restrict__ cwf, float* __restrict__ cbf,
                         const int* __restrict__ flag)
{
    int i = blockIdx.x * 256 + threadIdx.x;
    if (*flag == 0)
        prep_body<float>(i, (const float*)W1, (const float*)W2, (const float*)lw1,
                         (const float*)lw2, (const float*)b1, (const float*)b2,
                         (const float*)lb1, (const float*)lb2,
                         (const float*)cw, (const float*)cb,
                         W1t, W2t, lw1t, lw2t, b1f, b2f, lb1f, lb2f, cwf, cbf);
    else
        prep_body<bf16>(i, (const bf16*)W1, (const bf16*)W2, (const bf16*)lw1,
                        (const bf16*)lw2, (const bf16*)b1, (const bf16*)b2,
                        (const bf16*)lb1, (const bf16*)lb2,
                        (const bf16*)cw, (const bf16*)cb,
                        W1t, W2t, lw1t, lw2t, b1f, b2f, lb1f, lb2f, cwf, cbf);
}

// ---------------------------------------------------------------------------
// CSR build: deg histogram (+ fused gstart) -> two-level scan -> fill
// ---------------------------------------------------------------------------
__global__ __launch_bounds__(256)
void deg_gstart_kernel(const int* __restrict__ dst, int* __restrict__ deg,
                       const int* __restrict__ n2g, int* __restrict__ gstart)
{
    int b = blockIdx.x;
    int t = threadIdx.x;
    if (b < DEG_BLKS) {
        int e = b * 256 + t;
        if (e < N_EDGES) atomicAdd(&deg[dst[e]], 1);
        return;
    }
    int n = (b - DEG_BLKS) * 256 + t;
    if (n > N_NODES) return;
    if (n == N_NODES) {
        int last = n2g[N_NODES - 1];
        for (int g = last + 1; g <= N_GRAPHS; g++) gstart[g] = N_NODES;
        return;
    }
    int v = n2g[n];
    int prev = (n == 0) ? -1 : n2g[n - 1];
    for (int g = prev + 1; g <= v; g++) gstart[g] = n;
}

__global__ __launch_bounds__(256)
void scan_partial_kernel(const int* __restrict__ deg, int* __restrict__ part)
{
    int c = blockIdx.x, t = threadIdx.x;
    int i0 = c * SCAN_CHUNK + t * 4;
    int s = 0;
#pragma unroll
    for (int j = 0; j < 4; j++) {
        int i = i0 + j;
        if (i < N_NODES) s += deg[i];
    }
    __shared__ int red[256];
    red[t] = s;
    __syncthreads();
    for (int off = 128; off > 0; off >>= 1) {
        if (t < off) red[t] += red[t + off];
        __syncthreads();
    }
    if (t == 0) part[c] = red[0];
}

__global__ void scan_parts_kernel(int* __restrict__ part, int* __restrict__ edge_start)
{
    int run = 0;
    for (int c = 0; c < NCHK; c++) { int v = part[c]; part[c] = run; run += v; }
    edge_start[N_NODES] = run;
}

// also initializes cursor[] (saves a dispatch)
__global__ __launch_bounds__(256)
void scan_final_kernel(const int* __restrict__ deg, const int* __restrict__ part,
                       int* __restrict__ edge_start, int* __restrict__ cursor)
{
    int c = blockIdx.x, t = threadIdx.x;
    int i0 = c * SCAN_CHUNK + t * 4;
    int d[4];
    int tsum = 0;
#pragma unroll
    for (int j = 0; j < 4; j++) {
        int i = i0 + j;
        d[j] = (i < N_NODES) ? deg[i] : 0;
        tsum += d[j];
    }
    __shared__ int s[256];
    s[t] = tsum;
    __syncthreads();
    for (int off = 1; off < 256; off <<= 1) {
        int v = (t >= off) ? s[t - off] : 0;
        __syncthreads();
        s[t] += v;
        __syncthreads();
    }
    int run = part[c] + s[t] - tsum;
#pragma unroll
    for (int j = 0; j < 4; j++) {
        int i = i0 + j;
        if (i < N_NODES) { edge_start[i] = run; cursor[i] = run; run += d[j]; }
    }
}

__global__ __launch_bounds__(256)
void fill_kernel(const int* __restrict__ src, const int* __restrict__ dst,
                 int* __restrict__ cursor, int* __restrict__ csr_src)
{
    int e = blockIdx.x * 256 + threadIdx.x;
    if (e >= N_EDGES) return;
    int p = atomicAdd(&cursor[dst[e]], 1);
    csr_src[p] = src[e];
}

// ---------------------------------------------------------------------------
// Layer-1 gather (UNIFIED): agg1[n,0:128] = sum_{e: dst=n} feat[src[e],0:128]
// ---------------------------------------------------------------------------
__global__ __launch_bounds__(256)
void gather_feat_kernel(const void* __restrict__ feat_, const int* __restrict__ edge_start,
                        const int* __restrict__ csr_src, bf16* __restrict__ agg1,
                        const int* __restrict__ flag)
{
    int n = blockIdx.x * 4 + (threadIdx.x >> 6);
    if (n >= N_NODES) return;
    int lane = threadIdx.x & 63;
    int e0 = edge_start[n], e1 = edge_start[n + 1];
    float2 acc = {0.f, 0.f};
    if (*flag == 0) {
        const float* feat = (const float*)feat_;
        for (int i = e0; i < e1; i++) {
            int s = csr_src[i];
            float2 f = ((const float2*)(feat + (size_t)s * IN_DIM))[lane];
            acc.x += f.x; acc.y += f.y;
        }
    } else {
        const bf16* feat = (const bf16*)feat_;
        for (int i = e0; i < e1; i++) {
            int s = csr_src[i];
            float2 f = __bfloat1622float2(((const bf16x2*)(feat + (size_t)s * IN_DIM))[lane]);
            acc.x += f.x; acc.y += f.y;
        }
    }
    bf16x2 p;
    p.x = __float2bfloat16(acc.x);
    p.y = __float2bfloat16(acc.y);
    ((bf16x2*)(agg1 + (size_t)n * IN_DIM))[lane] = p;
}

// ---------------------------------------------------------------------------
// MFMA bf16 GEMM — BK=32, 3-buffer rotation, prefetch depth 2, counted vmcnt,
// register diet, __launch_bounds__(256,4). Template flags:
//   ACT=1: relu(A@Bt^T + bias); ACT=0: A@Bt^T.
//   FINAL=1 (head-2 only): skip the global C store; the relu'd x2 tile in Cs
//   feeds the 2-class dot directly (cwf/cbf fp32), writing d_out by dtype
//   flag. Kills final_layer dispatch + the 4 MB x2b round-trip.
// GEMM-core is the round-12 schedule verbatim (line closed after 5 nulls).
// ---------------------------------------------------------------------------
template<int NCT, int ACT, int FINAL>
__global__ __launch_bounds__(256, 4)
void mfma_gemm_kernel(const short* __restrict__ A, const short* __restrict__ Bt,
                      const float* __restrict__ biasf, bf16* __restrict__ Cout,
                      int M, int K, int nrt,
                      const float* __restrict__ cwf, const float* __restrict__ cbf,
                      const int* __restrict__ flag, void* __restrict__ outp)
{
    __shared__ short smem[24576];   // 3 bufs x 8192 shorts = 48 KB
    short* Cs = smem;               // epilogue alias

    // XCD-colocating decode
    const int b  = blockIdx.x;
    const int r8 = b & 7;
    const int t0 = b >> 3;
    const int x  = (t0 / NCT) * 8 + r8;
    const int y  = t0 % NCT;
    if (x >= nrt) return;
    const int row0 = x * 128;
    const int col0 = y * 128;

    const int tid  = threadIdx.x;
    const int lane = tid & 63;
    const int w    = tid >> 6;
    const int wr = w >> 1, wc = w & 1;
    const int m  = lane & 15, q = lane >> 4;

    // Staging (BK=32): per wave 2 A-chunks + 2 B-chunks (1 KB each).
    const int rr = lane >> 2;
    const int dc = ((lane & 3) ^ ((lane >> 3) & 3)) * 8;
    const short* pA = A  + (size_t)(row0 + w * 32 + rr) * K + dc;  // OOB: in-ws garbage
    const short* pB = Bt + (size_t)(col0 + w * 32 + rr) * K + dc;  // Bt padded
    const int cOff = 16 * K;            // chunk-1 row offset (wave-uniform)

    // Fragment-read swizzled slot offset (shorts): row m, granule q
    const int so = (q ^ ((m >> 1) & 3)) * 8;

    f32x4 acc[4][4];
#pragma unroll
    for (int i = 0; i < 4; i++)
#pragma unroll
        for (int j = 0; j < 4; j++) acc[i][j] = {0.f, 0.f, 0.f, 0.f};

    // Prologue: stage tile 0 -> buf0, tile 1 -> buf1 (8 loads/wave outstanding)
    {
        short* d = smem + w * 1024;
        gld16(pA, d);               gld16(pA + cOff, d + 512);
        gld16(pB, d + 4096);        gld16(pB + cOff, d + 4096 + 512);
        pA += 32; pB += 32;
        d = smem + 8192 + w * 1024;
        gld16(pA, d);               gld16(pA + cOff, d + 512);
        gld16(pB, d + 4096);        gld16(pB + cOff, d + 4096 + 512);
        pA += 32; pB += 32;
    }

    const int NT = K >> 5;
    int bc = 0;                         // compute-buffer offset (shorts)
    for (int t = 0; t < NT; ++t) {
        if (t + 2 < NT) {
            int bs2 = bc + 16384;       // buffer two ahead (mod 3)
            if (bs2 >= 24576) bs2 -= 24576;
            short* d = smem + bs2 + w * 1024;
            gld16(pA, d);           gld16(pA + cOff, d + 512);
            gld16(pB, d + 4096);    gld16(pB + cOff, d + 4096 + 512);
            pA += 32; pB += 32;
            asm volatile("s_waitcnt vmcnt(8)" ::: "memory");
        } else if (t + 2 == NT) {
            asm volatile("s_waitcnt vmcnt(4)" ::: "memory");
        } else {
            asm volatile("s_waitcnt vmcnt(0)" ::: "memory");
        }
        __builtin_amdgcn_s_barrier();   // raw: no implicit vmcnt(0) drain
        MEMFENCE;

        const short* Ab = smem + bc;
        const short* Bb = smem + bc + 4096;
        s8v av[4], bv[4];
#pragma unroll
        for (int rt = 0; rt < 4; rt++)
            av[rt] = *(const s8v*)&Ab[(wr * 64 + rt * 16 + m) * 32 + so];
#pragma unroll
        for (int ct = 0; ct < 4; ct++)
            bv[ct] = *(const s8v*)&Bb[(wc * 64 + ct * 16 + m) * 32 + so];
#pragma unroll
        for (int rt = 0; rt < 4; rt++)
#pragma unroll
            for (int ct = 0; ct < 4; ct++)
                acc[rt][ct] = __builtin_amdgcn_mfma_f32_16x16x32_bf16(
                    av[rt], bv[ct], acc[rt][ct], 0, 0, 0);

        MEMFENCE;
        __builtin_amdgcn_s_barrier();   // buf bc free for reuse at next stage
        MEMFENCE;
        bc = (bc == 16384) ? 0 : bc + 8192;
    }

    // Epilogue phase 1: (ACT: bias + relu) -> bf16 C-tile into LDS (pad-136)
#pragma unroll
    for (int rt = 0; rt < 4; rt++) {
#pragma unroll
        for (int ct = 0; ct < 4; ct++) {
            int lcol = wc * 64 + ct * 16 + m;
            float bv = ACT ? biasf[col0 + lcol] : 0.f;
#pragma unroll
            for (int reg = 0; reg < 4; reg++) {
                int lrow = wr * 64 + rt * 16 + q * 4 + reg;
                float v = acc[rt][ct][reg];
                if constexpr (ACT) {
                    v += bv;
                    v = v > 0.f ? v : 0.f;
                }
                Cs[lrow * 136 + lcol] = f2bs(v);
            }
        }
    }
    __syncthreads();

    if constexpr (FINAL) {
        // Fused classifier: out[row, c] = x2[row,0:100] . cwf[:,c] + cbf[c]
        // (x2 tile lives in Cs; thread = (row-in-tile, class))
        int r = tid >> 1, c = tid & 1;
        int row = row0 + r;
        if (row < M) {
            float acc2 = cbf[c];
#pragma unroll 4
            for (int k = 0; k < MLP2_OUT; k++)
                acc2 += bs2f(Cs[r * 136 + k]) * cwf[k * N_CLASSES + c];
            if (*flag == 0) ((float*)outp)[row * N_CLASSES + c] = acc2;
            else ((bf16*)outp)[row * N_CLASSES + c] = __float2bfloat16(acc2);
        }
    } else {
        // Epilogue phase 2: coalesced 16B stores (wave = 4 full 256B row segs)
#pragma unroll
        for (int it = 0; it < 8; it++) {
            int idx = it * 256 + tid;
            int r = idx >> 4;
            int c = (idx & 15) * 8;
            int row = row0 + r;
            if (row < M)
                *(float4*)&Cout[(size_t)row * HID + col0 + c] =
                    *(const float4*)&Cs[r * 136 + c];
        }
    }
}

// ---------------------------------------------------------------------------
// FUSED layer-2 gather + bias + relu + graph MEAN-pool, NO atomics, writing
// xinb cols 0..511 DIRECTLY (bf16, stride 768; mean = sum / node count).
// Round-14 fix: xinb is now a DEDICATED buffer (round-13 placed it at R_A
// offset 0, aliasing G rows 0..~6290 while other blocks still read G ->
// absmax 1.1e-2 fail). Round-9 geometry: block (4 waves) per graph, wave w
// strides nodes by 4; read rate at the random-row-gather ceiling (~2.6 TB/s).
// ---------------------------------------------------------------------------
__global__ __launch_bounds__(256)
void gather_pool_kernel(const bf16* __restrict__ G, const int* __restrict__ edge_start,
                        const int* __restrict__ csr_src, const int* __restrict__ gstart,
                        const float* __restrict__ b2f, bf16* __restrict__ xinb)
{
    __shared__ float red[4][HID];
    const int g = blockIdx.x;
    const int tid = threadIdx.x;
    const int lane = tid & 63;
    const int w = tid >> 6;

    float bj[8];
    {
        const float4* bp = (const float4*)(b2f + lane * 8);
        float4 b0 = bp[0], b1 = bp[1];
        bj[0] = b0.x; bj[1] = b0.y; bj[2] = b0.z; bj[3] = b0.w;
        bj[4] = b1.x; bj[5] = b1.y; bj[6] = b1.z; bj[7] = b1.w;
    }

    const int s0 = gstart[g], s1 = gstart[g + 1];
    float hacc[8];
#pragma unroll
    for (int j = 0; j < 8; j++) hacc[j] = 0.f;

    for (int n = s0 + w; n < s1; n += 4) {
        int e0 = edge_start[n], e1 = edge_start[n + 1];
        float racc[8];
#pragma unroll
        for (int j = 0; j < 8; j++) racc[j] = 0.f;
        for (int e = e0; e < e1; ++e) {
            int s = csr_src[e];
            float4 r = ((const float4*)(G + (size_t)s * HID))[lane];
            const bf16x2* p = (const bf16x2*)&r;
#pragma unroll
            for (int qq = 0; qq < 4; qq++) {
                float2 f = __bfloat1622float2(p[qq]);
                racc[2 * qq] += f.x; racc[2 * qq + 1] += f.y;
            }
        }
#pragma unroll
        for (int j = 0; j < 8; j++) {
            float v = racc[j] + bj[j];
            hacc[j] += (v > 0.f ? v : 0.f);
        }
    }

    // LDS reduce 4 partial rows, then normalized bf16 write into xinb
    ((float4*)&red[w][lane * 8])[0] = make_float4(hacc[0], hacc[1], hacc[2], hacc[3]);
    ((float4*)&red[w][lane * 8])[1] = make_float4(hacc[4], hacc[5], hacc[6], hacc[7]);
    __syncthreads();
    float cnt = (float)(s1 - s0);
    float rcnt = 1.0f / (cnt > 1.0f ? cnt : 1.0f);
#pragma unroll
    for (int c = tid; c < HID; c += 256) {
        float s = red[0][c] + red[1][c] + red[2][c] + red[3][c];
        xinb[(size_t)g * XIN_PAD + c] = __float2bfloat16(s * rcnt);
    }
}

// xinb[g, c] for c in [512,768): desc (dtype by flag) or zero-pad
__global__ __launch_bounds__(256)
void desc_pad_kernel(const void* __restrict__ desc_, bf16* __restrict__ xinb,
                     const int* __restrict__ flag)
{
    int idx = blockIdx.x * 256 + threadIdx.x;
    if (idx >= N_GRAPHS * 256) return;
    int g = idx >> 8;
    int c = HID + (idx & 255);
    float v = 0.f;
    if (c < XIN_DIM) {
        size_t di = (size_t)g * N_DESC + (c - HID);
        v = (*flag == 0) ? ((const float*)desc_)[di]
                         : __bfloat162float(((const bf16*)desc_)[di]);
    }
    xinb[(size_t)g * XIN_PAD + c] = __float2bfloat16(v);
}

// ---------------------------------------------------------------------------
static inline size_t align_up(size_t x, size_t a) { return (x + a - 1) & ~(a - 1); }
static inline int swgrid(int nrt, int nct) { return ((nrt + 7) / 8) * 8 * nct; }

extern "C" void kernel_launch(void* const* d_in, const int* in_sizes, int n_in,
                              void* d_out, int out_size, void* d_ws, size_t ws_size,
                              hipStream_t stream)
{
    const void* features    = d_in[0];
    const void* descriptors = d_in[1];
    const int*  src         = (const int*)d_in[2];
    const int*  dst         = (const int*)d_in[3];
    const int*  node2graph  = (const int*)d_in[4];
    const void* W1          = d_in[5];
    const void* b1          = d_in[6];
    const void* W2          = d_in[7];
    const void* b2          = d_in[8];
    const void* lw1         = d_in[9];
    const void* lb1         = d_in[10];
    const void* lw2         = d_in[11];
    const void* lb2         = d_in[12];
    const void* cw          = d_in[13];
    const void* cb          = d_in[14];
    (void)in_sizes; (void)n_in; (void)out_size; (void)ws_size;

    // ---- Workspace layout (~211.5 MB; proven ws >= ~239 MB) ----
    // R_A (102.4 MB): agg1 bf16 [100000,128] -> G bf16 [100000,512] (=h1@W2)
    //                 -> x1b (G dead once gather_pool completes)
    // R_B (102.4 MB): h1 bf16 [100000,512]
    // xinb: DEDICATED 6.14 MB (round-13 lesson: must not alias live G)
    char* ws = (char*)d_ws;
    size_t off = 0;
    bf16* agg1 = (bf16*)(ws + off);
    bf16* G    = (bf16*)(ws + off);   // layer-2 pre-bias product h1@W2
    bf16* x1b  = (bf16*)(ws + off);   // head-1 output (G dead by then)
    off = align_up(off + (size_t)N_NODES * HID * sizeof(bf16), 256);   // 102.4 MB
    bf16* h1 = (bf16*)(ws + off);
    off = align_up(off + (size_t)N_NODES * HID * sizeof(bf16), 256);   // +102.4 MB
    bf16* xinb = (bf16*)(ws + off);
    off = align_up(off + (size_t)N_GRAPHS * XIN_PAD * sizeof(bf16), 256); // +6.14 MB
    int* dflag = (int*)(ws + off);          off = align_up(off + 256, 256);
    int* edge_start = (int*)(ws + off);     off = align_up(off + (N_NODES + 1) * 4, 256);
    int* cursor = (int*)(ws + off);         off = align_up(off + N_NODES * 4, 256);
    int* csr_src = (int*)(ws + off);        off = align_up(off + N_EDGES * 4, 256);
    int* part = (int*)(ws + off);           off = align_up(off + NCHK * 4, 256);
    int* deg = (int*)(ws + off);            off = align_up(off + N_NODES * 4, 256);
    int* gstart = (int*)(ws + off);         off = align_up(off + (N_GRAPHS + 1) * 4, 256);
    short* W1t  = (short*)(ws + off);       off = align_up(off + (size_t)HID * IN_DIM * 2, 256);
    short* W2t  = (short*)(ws + off);       off = align_up(off + (size_t)HID * HID * 2, 256);
    short* lw1t = (short*)(ws + off);       off = align_up(off + (size_t)512 * XIN_PAD * 2, 256);
    short* lw2t = (short*)(ws + off);       off = align_up(off + (size_t)128 * HID * 2, 256);
    float* b1f  = (float*)(ws + off);       off = align_up(off + 512 * 4, 256);
    float* b2f  = (float*)(ws + off);       off = align_up(off + 512 * 4, 256);
    float* lb1f = (float*)(ws + off);       off = align_up(off + 512 * 4, 256);
    float* lb2f = (float*)(ws + off);       off = align_up(off + 128 * 4, 256);
    float* cwf  = (float*)(ws + off);       off = align_up(off + 256 * 4, 256);
    float* cbf  = (float*)(ws + off);       off = align_up(off + 64 * 4, 256);

    // ---- Detect float-tensor dtype (flag: 0=fp32, 1=bf16) ----
    detect_dtype_kernel<<<1, 256, 0, stream>>>(
        (const unsigned*)features, (unsigned)(N_NODES * IN_DIM / 2), dflag);

    // ---- Weight prep (single unified launch) ----
    {
        int nblk = (788416 + 255) / 256;
        prep_weights_kernel<<<nblk, 256, 0, stream>>>(
            W1, W2, lw1, lw2, b1, b2, lb1, lb2, cw, cb,
            W1t, W2t, lw1t, lw2t, b1f, b2f, lb1f, lb2f, cwf, cbf, dflag);
    }

    // ---- CSR build (counting sort by dst) + graph ranges ----
    hipMemsetAsync(deg, 0, N_NODES * 4, stream);
    {
        int gblk = (N_NODES + 256) / 256;          // covers n <= N_NODES
        deg_gstart_kernel<<<DEG_BLKS + gblk, 256, 0, stream>>>(
            dst, deg, node2graph, gstart);
    }
    scan_partial_kernel<<<NCHK, 256, 0, stream>>>(deg, part);
    scan_parts_kernel<<<1, 1, 0, stream>>>(part, edge_start);
    scan_final_kernel<<<NCHK, 256, 0, stream>>>(deg, part, edge_start, cursor);
    fill_kernel<<<(N_EDGES + 255) / 256, 256, 0, stream>>>(src, dst, cursor, csr_src);

    // ---- Layer 1: gather -> agg1 (bf16), MFMA GEMM (bias+relu) -> h1 ----
    gather_feat_kernel<<<N_NODES / 4, 256, 0, stream>>>(
        features, edge_start, csr_src, agg1, dflag);
    {
        int nrt = (N_NODES + 127) / 128;   // 782
        mfma_gemm_kernel<4, 1, 0><<<swgrid(nrt, 4), 256, 0, stream>>>(
            (const short*)agg1, W1t, b1f, h1, N_NODES, IN_DIM, nrt,
            nullptr, nullptr, nullptr, nullptr);
    }

    // ---- Layer 2 (reassociated): G = h1 @ W2, then fused
    //      gather+bias+relu+mean-pool -> xinb cols 0..511 ----
    {
        int nrt = (N_NODES + 127) / 128;
        mfma_gemm_kernel<4, 0, 0><<<swgrid(nrt, 4), 256, 0, stream>>>(
            (const short*)h1, W2t, b2f /*unused*/, G, N_NODES, HID, nrt,
            nullptr, nullptr, nullptr, nullptr);
    }
    gather_pool_kernel<<<N_GRAPHS, 256, 0, stream>>>(
        G, edge_start, csr_src, gstart, b2f, xinb);
    desc_pad_kernel<<<(N_GRAPHS * 256) / 256, 256, 0, stream>>>(
        descriptors, xinb, dflag);

    // ---- Head: x1 GEMM, then x2 GEMM with FUSED classifier epilogue ----
    {   // x1b[4000,512] = relu(xinb[4000,768] @ lw1t^T + lb1f)
        int nrt = (N_GRAPHS + 127) / 128;  // 32
        mfma_gemm_kernel<4, 1, 0><<<swgrid(nrt, 4), 256, 0, stream>>>(
            (const short*)xinb, lw1t, lb1f, x1b, N_GRAPHS, XIN_PAD, nrt,
            nullptr, nullptr, nullptr, nullptr);
    }
    {   // x2 tile (relu(x1b @ lw2t^T + lb2f)) -> in-LDS classifier -> d_out
        int nrt = (N_GRAPHS + 127) / 128;
        mfma_gemm_kernel<1, 1, 1><<<swgrid(nrt, 1), 256, 0, stream>>>(
            (const short*)x1b, lw2t, lb2f, nullptr, N_GRAPHS, HID, nrt,
            cwf, cbf, dflag, d_out);
    }
}